// Round 9
// baseline (2335.385 us; speedup 1.0000x reference)
//
#include <hip/hip_runtime.h>
#include <hip/hip_bf16.h>

// B=16, T=2048, D=2048, K(msg)=4, C=128, KC=512, CODEBOOK=512
#define M_BT      32768
#define KC_DIM    512
#define D_DIM     2048
#define C_DIM     128
#define NROWS     131072
#define NCODES    512
#define NELEM     16777216   // NROWS*C_DIM

typedef __bf16 bf16x8 __attribute__((ext_vector_type(8)));
typedef float  f32x4  __attribute__((ext_vector_type(4)));

#define AS3(p) ((__attribute__((address_space(3))) void*)(p))
#define AS1(p) ((const __attribute__((address_space(1))) void*)(p))

static __device__ __forceinline__ ushort f2bf(float x) {
    unsigned u = __float_as_uint(x);
    unsigned r = (u + 0x7fffu + ((u >> 16) & 1u)) >> 16;
    return (ushort)r;
}
static __device__ __forceinline__ float bf2f(ushort u) {
    return __uint_as_float(((unsigned)u) << 16);
}

// ---------------- zero counters ----------------
__global__ __launch_bounds__(512)
void zero_kernel(unsigned* __restrict__ counts, float* __restrict__ loss_sum) {
    counts[threadIdx.x] = 0u;
    if (threadIdx.x == 0) loss_sum[0] = 0.f;
}

// ---------------- numpy-pairwise sum of squares per 128-row ----------------
__global__ __launch_bounds__(256)
void sq_pairwise(const float* __restrict__ src, float* __restrict__ dst, int nrows) {
    int t = threadIdx.x;
    int row = blockIdx.x * 32 + (t >> 3);
    int j = t & 7;
    if (row >= nrows) return;
    const float* p = src + (size_t)row * C_DIM + j;
    float v = p[0];
    float r = __fmul_rn(v, v);
#pragma unroll
    for (int i = 1; i < 16; ++i) {
        float u = p[i * 8];
        r = __fadd_rn(r, __fmul_rn(u, u));
    }
    r = __fadd_rn(r, __shfl_xor(r, 1));
    r = __fadd_rn(r, __shfl_xor(r, 2));
    r = __fadd_rn(r, __shfl_xor(r, 4));
    if (j == 0) dst[row] = r;
}

// ---------------- encoder GEMM: 128x64 tile, 8x4 micro, kc=384 folds ----------------
// 2-phase dbuf pipeline, static buffers (even tiles->As0/Bs0, odd->As1/Bs1),
// counted vmcnt(6), persistent +32 staged pointers. FMA order identical to r3/r7.
__global__ __launch_bounds__(256)
void enc_gemm(const float* __restrict__ A, const float* __restrict__ B,
              const float* __restrict__ bias, float* __restrict__ C)
{
    constexpr int K = D_DIM, N = KC_DIM;
    __shared__ __align__(128) float As0[4096], As1[4096];   // 128 rows x 32 k each
    __shared__ __align__(128) float Bs0[2048], Bs1[2048];   // 64 rows x 32 k each
    const int gid = blockIdx.x;                    // 2048 blocks
    const int f   = (gid & 7) * 256 + (gid >> 3);  // XCD-contiguous
    const int bx  = f & 7, by = f >> 3;
    const int row0 = by * 128, col0 = bx * 64;

    const int tid  = threadIdx.x;
    const int ty   = tid >> 4, tx = tid & 15;
    const int lane = tid & 63, wave = tid >> 6;

    float acc[8][4], accC[8][4];
#pragma unroll
    for (int i = 0; i < 8; ++i)
#pragma unroll
        for (int j = 0; j < 4; ++j) { acc[i][j] = 0.f; accC[i][j] = 0.f; }

    // staging mapping (identical to r7): LDS[row][slot] = G[row][slot ^ ((row>>3)&7)]
    const int lr = lane >> 3, lc = lane & 7;
    const int ac0 = lc ^ ((wave & 1) << 2);          // (wave*4)&7 = (wave&1)*4
    const int bc0 = lc ^ ((wave * 2) & 7);

    const float* pa0 = A + (size_t)(row0 + wave * 32 +  0 + lr) * K + ((ac0 ^ 0) << 2);
    const float* pa1 = A + (size_t)(row0 + wave * 32 +  8 + lr) * K + ((ac0 ^ 1) << 2);
    const float* pa2 = A + (size_t)(row0 + wave * 32 + 16 + lr) * K + ((ac0 ^ 2) << 2);
    const float* pa3 = A + (size_t)(row0 + wave * 32 + 24 + lr) * K + ((ac0 ^ 3) << 2);
    const float* pb0 = B + (size_t)(col0 + wave * 16 +  0 + lr) * K + ((bc0 ^ 0) << 2);
    const float* pb1 = B + (size_t)(col0 + wave * 16 +  8 + lr) * K + ((bc0 ^ 1) << 2);

    const int sa = ty & 7, sb = tx >> 1;

#define STAGE(Asb, Bsb) do {                                                        \
    __builtin_amdgcn_global_load_lds(AS1(pa0), AS3(&Asb[(wave * 4 + 0) * 256]), 16, 0, 0); \
    __builtin_amdgcn_global_load_lds(AS1(pa1), AS3(&Asb[(wave * 4 + 1) * 256]), 16, 0, 0); \
    __builtin_amdgcn_global_load_lds(AS1(pa2), AS3(&Asb[(wave * 4 + 2) * 256]), 16, 0, 0); \
    __builtin_amdgcn_global_load_lds(AS1(pa3), AS3(&Asb[(wave * 4 + 3) * 256]), 16, 0, 0); \
    __builtin_amdgcn_global_load_lds(AS1(pb0), AS3(&Bsb[(wave * 2 + 0) * 256]), 16, 0, 0); \
    __builtin_amdgcn_global_load_lds(AS1(pb1), AS3(&Bsb[(wave * 2 + 1) * 256]), 16, 0, 0); \
    pa0 += 32; pa1 += 32; pa2 += 32; pa3 += 32; pb0 += 32; pb1 += 32;               \
} while (0)

#define COMPUTE(Asb, Bsb) do {                                                      \
    const char* Ab_ = (const char*)&Asb[ty * 256] + (sa << 4);                      \
    const char* Bb_ = (const char*)&Bsb[tx * 128] + (sb << 4);                      \
    _Pragma("unroll")                                                               \
    for (int kk = 0; kk < 8; ++kk) {                                                \
        const char* ar_ = (const char*)((uintptr_t)Ab_ ^ (unsigned)(kk << 4));      \
        const char* br_ = (const char*)((uintptr_t)Bb_ ^ (unsigned)(kk << 4));      \
        float4 b4[4];                                                               \
        _Pragma("unroll")                                                           \
        for (int j = 0; j < 4; ++j) b4[j] = *(const float4*)(br_ + j * 128);        \
        _Pragma("unroll")                                                           \
        for (int i = 0; i < 8; ++i) {                                               \
            float4 a4 = *(const float4*)(ar_ + i * 128);                            \
            _Pragma("unroll")                                                       \
            for (int j = 0; j < 4; ++j) {                                           \
                float t_ = accC[i][j];                                              \
                t_ = fmaf(a4.x, b4[j].x, t_);                                       \
                t_ = fmaf(a4.y, b4[j].y, t_);                                       \
                t_ = fmaf(a4.z, b4[j].z, t_);                                       \
                t_ = fmaf(a4.w, b4[j].w, t_);                                       \
                accC[i][j] = t_;                                                    \
            }                                                                       \
        }                                                                           \
    }                                                                               \
} while (0)

#define FOLD() do {                                                                 \
    _Pragma("unroll")                                                               \
    for (int i = 0; i < 8; ++i)                                                     \
        _Pragma("unroll")                                                           \
        for (int j = 0; j < 4; ++j) {                                               \
            acc[i][j] = __fadd_rn(acc[i][j], accC[i][j]);                           \
            accC[i][j] = 0.f;                                                       \
        }                                                                           \
} while (0)

    STAGE(As0, Bs0);                                   // tile 0
    int foldcnt = 6;                                   // fold after odd tiles 11,23,35,47,59
#pragma unroll 1
    for (int i = 0; i < 31; ++i) {                     // tiles 2i, 2i+1
        STAGE(As1, Bs1);                               // tile 2i+1
        asm volatile("s_waitcnt vmcnt(6)" ::: "memory");
        __builtin_amdgcn_s_barrier();
        COMPUTE(As0, Bs0);                             // tile 2i (even: never a fold)
        __builtin_amdgcn_s_barrier();
        STAGE(As0, Bs0);                               // tile 2i+2
        asm volatile("s_waitcnt vmcnt(6)" ::: "memory");
        __builtin_amdgcn_s_barrier();
        COMPUTE(As1, Bs1);                             // tile 2i+1
        if (--foldcnt == 0) { FOLD(); foldcnt = 6; }   // (2i+2)%12==0 boundaries
        __builtin_amdgcn_s_barrier();
    }
    STAGE(As1, Bs1);                                   // tile 63
    asm volatile("s_waitcnt vmcnt(6)" ::: "memory");
    __builtin_amdgcn_s_barrier();
    COMPUTE(As0, Bs0);                                 // tile 62
    asm volatile("s_waitcnt vmcnt(0)" ::: "memory");
    __builtin_amdgcn_s_barrier();
    COMPUTE(As1, Bs1);                                 // tile 63
    FOLD();                                            // K%384=128 remainder

#undef STAGE
#undef COMPUTE
#undef FOLD

    float bv[4];
#pragma unroll
    for (int j = 0; j < 4; ++j) bv[j] = bias[col0 + tx * 4 + j];
#pragma unroll
    for (int i = 0; i < 8; ++i) {
        size_t r = (size_t)(row0 + ty * 8 + i) * N + col0 + tx * 4;
        float4 o;
        o.x = __fadd_rn(acc[i][0], bv[0]); o.y = __fadd_rn(acc[i][1], bv[1]);
        o.z = __fadd_rn(acc[i][2], bv[2]); o.w = __fadd_rn(acc[i][3], bv[3]);
        *(float4*)(C + r) = o;
    }
}

// ---------------- dist GEMM: 128x128, 8x8, K=128, argmin epilogue ----------------
__global__ __launch_bounds__(256)
void dist_gemm(const float* __restrict__ A, const float* __restrict__ B,
               const float* __restrict__ xsq, const float* __restrict__ esq,
               float* __restrict__ pmin, int* __restrict__ pidx)
{
    constexpr int K = C_DIM;
    __shared__ __align__(128) float As[4096];
    __shared__ __align__(128) float Bs[4096];
    const int tid  = threadIdx.x;
    const int ty   = tid >> 4, tx = tid & 15;
    const int lane = tid & 63, wave = tid >> 6;
    const int row0 = blockIdx.y * 128, col0 = blockIdx.x * 128;

    float acc[8][8];
#pragma unroll
    for (int i = 0; i < 8; ++i)
#pragma unroll
        for (int j = 0; j < 8; ++j) acc[i][j] = 0.f;

    size_t aoff[4], boff[4];
    int lb[4];
#pragma unroll
    for (int rr = 0; rr < 4; ++rr) {
        const int g = wave * 4 + rr;
        const int r = g * 8 + (lane >> 3);
        const int c = (lane & 7) ^ (g & 7);
        aoff[rr] = (size_t)(row0 + r) * K + c * 4;
        boff[rr] = (size_t)(col0 + r) * K + c * 4;
        lb[rr]   = g * 256;
    }

    const int sa = ty & 7, sb = tx & 7;

    for (int k0 = 0; k0 < K; k0 += 32) {
#pragma unroll
        for (int rr = 0; rr < 4; ++rr) {
            __builtin_amdgcn_global_load_lds(AS1(A + aoff[rr] + k0), AS3(As + lb[rr]), 16, 0, 0);
            __builtin_amdgcn_global_load_lds(AS1(B + boff[rr] + k0), AS3(Bs + lb[rr]), 16, 0, 0);
        }
        __syncthreads();

        const char* Ab = (const char*)&As[ty * 8 * 32] + (sa << 4);
        const char* Bb = (const char*)&Bs[tx * 8 * 32] + (sb << 4);
#pragma unroll
        for (int kk = 0; kk < 8; ++kk) {
            const char* ar = (const char*)((uintptr_t)Ab ^ (unsigned)(kk << 4));
            const char* br = (const char*)((uintptr_t)Bb ^ (unsigned)(kk << 4));
            float4 b4[8];
#pragma unroll
            for (int j = 0; j < 8; ++j)
                b4[j] = *(const float4*)(br + j * 128);
#pragma unroll
            for (int i = 0; i < 8; ++i) {
                float4 a4 = *(const float4*)(ar + i * 128);
#pragma unroll
                for (int j = 0; j < 8; ++j) {
                    float t = acc[i][j];
                    t = fmaf(a4.x, b4[j].x, t);
                    t = fmaf(a4.y, b4[j].y, t);
                    t = fmaf(a4.z, b4[j].z, t);
                    t = fmaf(a4.w, b4[j].w, t);
                    acc[i][j] = t;
                }
            }
        }
        __syncthreads();
    }

    float (*rmin)[16] = (float (*)[16])As;
    int   (*ridx)[16] = (int (*)[16])Bs;
    float es[8];
#pragma unroll
    for (int j = 0; j < 8; ++j) es[j] = esq[col0 + tx * 8 + j];
#pragma unroll
    for (int i = 0; i < 8; ++i) {
        float xs = xsq[row0 + ty * 8 + i];
        float b = __fadd_rn(__fsub_rn(xs, __fmul_rn(2.0f, acc[i][0])), es[0]);
        int bi = col0 + tx * 8;
#pragma unroll
        for (int j = 1; j < 8; ++j) {
            float d = __fadd_rn(__fsub_rn(xs, __fmul_rn(2.0f, acc[i][j])), es[j]);
            if (d < b) { b = d; bi = col0 + tx * 8 + j; }
        }
        rmin[ty * 8 + i][tx] = b;
        ridx[ty * 8 + i][tx] = bi;
    }
    __syncthreads();
    if (tid < 128) {
        float b = rmin[tid][0]; int ix = ridx[tid][0];
#pragma unroll
        for (int t = 1; t < 16; ++t) {
            if (rmin[tid][t] < b) { b = rmin[tid][t]; ix = ridx[tid][t]; }
        }
        size_t o = (size_t)(row0 + tid) * gridDim.x + blockIdx.x;
        pmin[o] = b; pidx[o] = ix;
    }
}

// ---------------- merge 4 col-blocks -> final idx + histogram ----------------
__global__ __launch_bounds__(256)
void finalize_idx(const float* __restrict__ pmin, const int* __restrict__ pidx,
                  int* __restrict__ idx_int, float* __restrict__ idx_f,
                  unsigned* __restrict__ counts) {
    __shared__ unsigned hist[NCODES];
    int t = threadIdx.x;
    hist[t] = 0u; hist[t + 256] = 0u;
    __syncthreads();
    int row = blockIdx.x * 256 + t;
    size_t base = (size_t)row * 4;
    float b = pmin[base]; int ix = pidx[base];
#pragma unroll
    for (int nb = 1; nb < 4; ++nb) {
        float v = pmin[base + nb];
        if (v < b) { b = v; ix = pidx[base + nb]; }
    }
    idx_int[row] = ix;
    idx_f[row] = (float)ix;
    atomicAdd(&hist[ix], 1u);
    __syncthreads();
    if (hist[t]) atomicAdd(&counts[t], hist[t]);
    if (hist[t + 256]) atomicAdd(&counts[t + 256], hist[t + 256]);
}

// ---------------- split codebook / dec_w into bf16 hi+lo ----------------
__global__ __launch_bounds__(256)
void split_hi_lo(const float* __restrict__ src, ushort* __restrict__ hi,
                 ushort* __restrict__ lo, int n4) {
    int e = blockIdx.x * 256 + threadIdx.x;
    if (e >= n4) return;
    float4 v = *(const float4*)&src[(size_t)e * 4];
    ushort h0 = f2bf(v.x), h1 = f2bf(v.y), h2 = f2bf(v.z), h3 = f2bf(v.w);
    ushort l0 = f2bf(v.x - bf2f(h0)), l1 = f2bf(v.y - bf2f(h1));
    ushort l2 = f2bf(v.z - bf2f(h2)), l3 = f2bf(v.w - bf2f(h3));
    ushort4 H; H.x = h0; H.y = h1; H.z = h2; H.w = h3;
    ushort4 L; L.x = l0; L.y = l1; L.z = l2; L.w = l3;
    *(ushort4*)&hi[(size_t)e * 4] = H;
    *(ushort4*)&lo[(size_t)e * 4] = L;
}

// ---------------- loss only (reads flat, does NOT modify it) ----------------
__global__ __launch_bounds__(256)
void gather_loss(const float* __restrict__ flat, const int* __restrict__ idx,
                 const float* __restrict__ cb, float* __restrict__ loss_sum) {
    size_t e0 = ((size_t)blockIdx.x * 256 + threadIdx.x) * 8;
    int n = (int)(e0 >> 7);
    int c = (int)(e0 & 127);
    int k = idx[n];
    const float4* qp = (const float4*)(cb + (size_t)k * C_DIM + c);
    float4 q0 = qp[0], q1 = qp[1];
    const float4* fp = (const float4*)(flat + e0);
    float4 f0 = fp[0], f1 = fp[1];
    float s = 0.f, d;
    d = q0.x - f0.x; s += d * d;  d = q0.y - f0.y; s += d * d;
    d = q0.z - f0.z; s += d * d;  d = q0.w - f0.w; s += d * d;
    d = q1.x - f1.x; s += d * d;  d = q1.y - f1.y; s += d * d;
    d = q1.z - f1.z; s += d * d;  d = q1.w - f1.w; s += d * d;

    __shared__ float redf[256];
    redf[threadIdx.x] = s;
    __syncthreads();
    for (int st = 128; st; st >>= 1) {
        if (threadIdx.x < st) redf[threadIdx.x] += redf[threadIdx.x + st];
        __syncthreads();
    }
    if (threadIdx.x == 0) atomicAdd(loss_sum, redf[0]);
}

// ---------------- gather split-bf16 quantized rows ----------------
__global__ __launch_bounds__(256)
void build_q(const int* __restrict__ idx, const ushort* __restrict__ cbh,
             const ushort* __restrict__ cbl, ushort* __restrict__ Qh,
             ushort* __restrict__ Ql) {
    int t = blockIdx.x * 256 + threadIdx.x;   // 16B chunk id
    int n = t >> 4, c8 = t & 15;
    int k = idx[n];
    uint4 vh = *(const uint4*)&cbh[(size_t)k * C_DIM + c8 * 8];
    uint4 vl = *(const uint4*)&cbl[(size_t)k * C_DIM + c8 * 8];
    *(uint4*)&Qh[(size_t)n * C_DIM + c8 * 8] = vh;
    *(uint4*)&Ql[(size_t)n * C_DIM + c8 * 8] = vl;
}

// ---------------- decoder: split-bf16 MFMA GEMM, XCD-swizzled 1-D grid ----------------
__global__ __launch_bounds__(256)
void dec_gemm_bf16(const ushort* __restrict__ Qh, const ushort* __restrict__ Ql,
                   const ushort* __restrict__ Wh, const ushort* __restrict__ Wl,
                   const float* __restrict__ bias, float* __restrict__ C)
{
    constexpr int Kd = 512, Nd = 2048;
    __shared__ ushort Ah[128 * 32], Al[128 * 32], Bh[128 * 32], Bl[128 * 32];
    const int gid = blockIdx.x;                       // 4096 blocks
    const int f   = (gid & 7) * 512 + (gid >> 3);
    const int bx  = f & 15, by = f >> 4;
    const int tid  = threadIdx.x;
    const int lane = tid & 63, wave = tid >> 6;
    const int wm = wave >> 1, wn = wave & 1;
    const int row0 = by * 128, col0 = bx * 128;

    f32x4 acc[4][4];
#pragma unroll
    for (int i = 0; i < 4; ++i)
#pragma unroll
        for (int j = 0; j < 4; ++j)
#pragma unroll
            for (int q = 0; q < 4; ++q) acc[i][j][q] = 0.f;

    const int fr = lane & 15, s4 = lane >> 4;

    for (int kt = 0; kt < Kd / 32; ++kt) {
        const int k0 = kt * 32;
#pragma unroll
        for (int r = 0; r < 2; ++r) {
            const int t2 = r * 256 + wave * 64 + lane;
            const int ro = t2 >> 2, sb = t2 & 3;
            const int base = (r * 256 + wave * 64) * 8;
            const size_t ga = (size_t)(row0 + ro) * Kd + k0 + sb * 8;
            const size_t gb = (size_t)(col0 + ro) * Kd + k0 + sb * 8;
            __builtin_amdgcn_global_load_lds(AS1(Qh + ga), AS3(&Ah[base]), 16, 0, 0);
            __builtin_amdgcn_global_load_lds(AS1(Ql + ga), AS3(&Al[base]), 16, 0, 0);
            __builtin_amdgcn_global_load_lds(AS1(Wh + gb), AS3(&Bh[base]), 16, 0, 0);
            __builtin_amdgcn_global_load_lds(AS1(Wl + gb), AS3(&Bl[base]), 16, 0, 0);
        }
        __syncthreads();

        bf16x8 ah[4], al[4], bh[4], bl[4];
#pragma unroll
        for (int mi = 0; mi < 4; ++mi) {
            const int off = (wm * 64 + mi * 16 + fr) * 32 + s4 * 8;
            ah[mi] = *(const bf16x8*)&Ah[off];
            al[mi] = *(const bf16x8*)&Al[off];
        }
#pragma unroll
        for (int ni = 0; ni < 4; ++ni) {
            const int off = (wn * 64 + ni * 16 + fr) * 32 + s4 * 8;
            bh[ni] = *(const bf16x8*)&Bh[off];
            bl[ni] = *(const bf16x8*)&Bl[off];
        }
#pragma unroll
        for (int mi = 0; mi < 4; ++mi)
#pragma unroll
            for (int ni = 0; ni < 4; ++ni) {
                acc[mi][ni] = __builtin_amdgcn_mfma_f32_16x16x32_bf16(ah[mi], bh[ni], acc[mi][ni], 0, 0, 0);
                acc[mi][ni] = __builtin_amdgcn_mfma_f32_16x16x32_bf16(ah[mi], bl[ni], acc[mi][ni], 0, 0, 0);
                acc[mi][ni] = __builtin_amdgcn_mfma_f32_16x16x32_bf16(al[mi], bh[ni], acc[mi][ni], 0, 0, 0);
            }
        __syncthreads();
    }

#pragma unroll
    for (int ni = 0; ni < 4; ++ni) {
        const int c = col0 + wn * 64 + ni * 16 + fr;
        const float bv = bias[c];
#pragma unroll
        for (int mi = 0; mi < 4; ++mi) {
            const int r = row0 + wm * 64 + mi * 16 + s4 * 4;
#pragma unroll
            for (int q = 0; q < 4; ++q)
                C[(size_t)(r + q) * Nd + c] = acc[mi][ni][q] + bv;
        }
    }
}

// ---------------- scalars ----------------
__global__ __launch_bounds__(512)
void finalize_scalars(const unsigned* __restrict__ counts,
                      const float* __restrict__ loss_sum, float* __restrict__ out5) {
    __shared__ float rent[512];
    __shared__ float ruse[512];
    int t = threadIdx.x;
    float c = (float)counts[t];
    float avg = c * (1.0f / (float)NROWS);
    rent[t] = avg * logf(avg + 1e-10f);
    ruse[t] = counts[t] > 0u ? 1.f : 0.f;
    __syncthreads();
    for (int st = 256; st; st >>= 1) {
        if (t < st) { rent[t] += rent[t + st]; ruse[t] += ruse[t + st]; }
        __syncthreads();
    }
    if (t == 0) {
        float H = -rent[0];
        float perp = expf(H);
        float cl = loss_sum[0] * (1.0f / (float)NELEM);
        out5[0] = cl + 0.25f * cl;
        out5[1] = cl;
        out5[2] = cl;
        out5[3] = perp;
        out5[4] = ruse[0] * (1.0f / (float)NCODES);
    }
}

extern "C" void kernel_launch(void* const* d_in, const int* in_sizes, int n_in,
                              void* d_out, int out_size, void* d_ws, size_t ws_size,
                              hipStream_t stream) {
    const float* h     = (const float*)d_in[0];
    const float* enc_w = (const float*)d_in[1];
    const float* enc_b = (const float*)d_in[2];
    const float* cb    = (const float*)d_in[3];
    const float* dec_w = (const float*)d_in[4];
    const float* dec_b = (const float*)d_in[5];
    float* out = (float*)d_out;

    float* ws = (float*)d_ws;
    float*    flat     = ws;                         // [0, 16777216)
    float*    xsq      = ws + 16777216;              // 131072 (dead after dist)
    float*    pmin     = ws + 16908288;              // 524288 (dead after finalize)
    int*      pidx     = (int*)(ws + 17432576);      // 524288 (dead after finalize)
    int*      idx_int  = (int*)(ws + 17956864);      // 131072
    float*    esq      = ws + 18087936;              // 512
    unsigned* counts   = (unsigned*)(ws + 18088448); // 512
    float*    loss_sum = ws + 18088960;              // 1

    // overlays (used only after their hosts are dead):
    ushort* Qh  = (ushort*)ws;                       // over flat
    ushort* Ql  = (ushort*)(ws + 8388608);           // over flat
    ushort* cbh = (ushort*)(ws + 16777216);          // over xsq
    ushort* cbl = (ushort*)(ws + 16809984);          // over xsq
    ushort* Wh  = (ushort*)(ws + 16842752);          // over xsq/pmin
    ushort* Wl  = (ushort*)(ws + 17367040);          // over pmin/pidx

    float* msg_out = out;                     // 67108864
    float* idx_out = out + 67108864;          // 131072
    float* sc_out  = out + 67108864 + 131072; // 5

    zero_kernel<<<1, 512, 0, stream>>>(counts, loss_sum);
    sq_pairwise<<<NCODES / 32, 256, 0, stream>>>(cb, esq, NCODES);

    // encoder: flat = h @ enc_w^T + enc_b (numpy kc=384 folds), 2-phase dbuf
    enc_gemm<<<2048, 256, 0, stream>>>(h, enc_w, enc_b, flat);

    sq_pairwise<<<NROWS / 32, 256, 0, stream>>>(flat, xsq, NROWS);

    // distances + per-colblock argmin
    dist_gemm<<<dim3(NCODES / 128, NROWS / 128), 256, 0, stream>>>(
        flat, cb, xsq, esq, pmin, pidx);

    finalize_idx<<<NROWS / 256, 256, 0, stream>>>(pmin, pidx, idx_int, idx_out, counts);

    // xsq/pmin/pidx now dead -> build bf16 splits in their space
    split_hi_lo<<<(NCODES * C_DIM / 4 + 255) / 256, 256, 0, stream>>>(cb, cbh, cbl, NCODES * C_DIM / 4);
    split_hi_lo<<<(D_DIM * KC_DIM / 4 + 255) / 256, 256, 0, stream>>>(dec_w, Wh, Wl, D_DIM * KC_DIM / 4);

    gather_loss<<<NELEM / (256 * 8), 256, 0, stream>>>(flat, idx_int, cb, loss_sum);

    // flat now dead -> gather split-bf16 quantized rows into its space
    build_q<<<NROWS * 16 / 256, 256, 0, stream>>>(idx_int, cbh, cbl, Qh, Ql);

    // decoder on matrix cores, XCD-swizzled
    dec_gemm_bf16<<<4096, 256, 0, stream>>>(Qh, Ql, Wh, Wl, dec_b, msg_out);

    finalize_scalars<<<1, 512, 0, stream>>>(counts, loss_sum, sc_out);
}

// Round 10
// 2138.679 us; speedup vs baseline: 1.0920x; 1.0920x over previous
//
#include <hip/hip_runtime.h>
#include <hip/hip_bf16.h>

// B=16, T=2048, D=2048, K(msg)=4, C=128, KC=512, CODEBOOK=512
#define M_BT      32768
#define KC_DIM    512
#define D_DIM     2048
#define C_DIM     128
#define NROWS     131072
#define NCODES    512
#define NELEM     16777216   // NROWS*C_DIM

typedef __bf16 bf16x8 __attribute__((ext_vector_type(8)));
typedef float  f32x4  __attribute__((ext_vector_type(4)));

#define AS3(p) ((__attribute__((address_space(3))) void*)(p))
#define AS1(p) ((const __attribute__((address_space(1))) void*)(p))

static __device__ __forceinline__ ushort f2bf(float x) {
    unsigned u = __float_as_uint(x);
    unsigned r = (u + 0x7fffu + ((u >> 16) & 1u)) >> 16;
    return (ushort)r;
}
static __device__ __forceinline__ float bf2f(ushort u) {
    return __uint_as_float(((unsigned)u) << 16);
}

// ---------------- zero counters ----------------
__global__ __launch_bounds__(512)
void zero_kernel(unsigned* __restrict__ counts, float* __restrict__ loss_sum) {
    counts[threadIdx.x] = 0u;
    if (threadIdx.x == 0) loss_sum[0] = 0.f;
}

// ---------------- numpy-pairwise sum of squares per 128-row ----------------
__global__ __launch_bounds__(256)
void sq_pairwise(const float* __restrict__ src, float* __restrict__ dst, int nrows) {
    int t = threadIdx.x;
    int row = blockIdx.x * 32 + (t >> 3);
    int j = t & 7;
    if (row >= nrows) return;
    const float* p = src + (size_t)row * C_DIM + j;
    float v = p[0];
    float r = __fmul_rn(v, v);
#pragma unroll
    for (int i = 1; i < 16; ++i) {
        float u = p[i * 8];
        r = __fadd_rn(r, __fmul_rn(u, u));
    }
    r = __fadd_rn(r, __shfl_xor(r, 1));
    r = __fadd_rn(r, __shfl_xor(r, 2));
    r = __fadd_rn(r, __shfl_xor(r, 4));
    if (j == 0) dst[row] = r;
}

// ---------------- encoder GEMM: 128x64 tile, 8x4 micro, BK=64, kc=384 folds ----
// r7 structure (single-buffer, __syncthreads) with TWO 32-k subtiles staged per
// barrier period: 12 loads -> sync -> 16 kk compute -> sync. Same registers as
// r7 (reuses aoff/boff with +32 uniform). FMA/fold order bit-identical to r3/r7.
__global__ __launch_bounds__(256, 2)
void enc_gemm(const float* __restrict__ A, const float* __restrict__ B,
              const float* __restrict__ bias, float* __restrict__ C)
{
    constexpr int K = D_DIM, N = KC_DIM;
    __shared__ __align__(128) float As[8192];   // [2 subtiles][128 rows][32 k]
    __shared__ __align__(128) float Bs[4096];   // [2 subtiles][64 rows][32 k]
    const int gid = blockIdx.x;                    // 2048 blocks
    const int f   = (gid & 7) * 256 + (gid >> 3);  // XCD-contiguous
    const int bx  = f & 7, by = f >> 3;
    const int row0 = by * 128, col0 = bx * 64;

    const int tid  = threadIdx.x;
    const int ty   = tid >> 4, tx = tid & 15;
    const int lane = tid & 63, wave = tid >> 6;

    float acc[8][4], accC[8][4];
#pragma unroll
    for (int i = 0; i < 8; ++i)
#pragma unroll
        for (int j = 0; j < 4; ++j) { acc[i][j] = 0.f; accC[i][j] = 0.f; }

    // staging mapping (identical to r7): LDS[row][slot] = G[row][slot ^ ((row>>3)&7)]
    const int lr = lane >> 3, lc = lane & 7;
    const int ac0 = lc ^ ((wave & 1) << 2);          // (wave*4)&7
    const int bc0 = lc ^ ((wave * 2) & 7);

    size_t aoff[4], boff[2];
    int lba[4], lbb[2];
#pragma unroll
    for (int rr = 0; rr < 4; ++rr) {
        aoff[rr] = (size_t)(row0 + wave * 32 + rr * 8 + lr) * K + ((ac0 ^ rr) << 2);
        lba[rr]  = (wave * 4 + rr) * 256;
    }
#pragma unroll
    for (int rr = 0; rr < 2; ++rr) {
        boff[rr] = (size_t)(col0 + wave * 16 + rr * 8 + lr) * K + ((bc0 ^ rr) << 2);
        lbb[rr]  = (wave * 2 + rr) * 256;
    }

    const int sa = ty & 7, sb = tx >> 1;

#define COMPUTE(Ap, Bp) do {                                                        \
    const char* Ab_ = (const char*)&(Ap)[ty * 256] + (sa << 4);                     \
    const char* Bb_ = (const char*)&(Bp)[tx * 128] + (sb << 4);                     \
    _Pragma("unroll")                                                               \
    for (int kk = 0; kk < 8; ++kk) {                                                \
        const char* ar_ = (const char*)((uintptr_t)Ab_ ^ (unsigned)(kk << 4));      \
        const char* br_ = (const char*)((uintptr_t)Bb_ ^ (unsigned)(kk << 4));      \
        float4 b4[4];                                                               \
        _Pragma("unroll")                                                           \
        for (int j = 0; j < 4; ++j) b4[j] = *(const float4*)(br_ + j * 128);        \
        _Pragma("unroll")                                                           \
        for (int i = 0; i < 8; ++i) {                                               \
            float4 a4 = *(const float4*)(ar_ + i * 128);                            \
            _Pragma("unroll")                                                       \
            for (int j = 0; j < 4; ++j) {                                           \
                float t_ = accC[i][j];                                              \
                t_ = fmaf(a4.x, b4[j].x, t_);                                       \
                t_ = fmaf(a4.y, b4[j].y, t_);                                       \
                t_ = fmaf(a4.z, b4[j].z, t_);                                       \
                t_ = fmaf(a4.w, b4[j].w, t_);                                       \
                accC[i][j] = t_;                                                    \
            }                                                                       \
        }                                                                           \
    }                                                                               \
} while (0)

#define FOLD() do {                                                                 \
    _Pragma("unroll")                                                               \
    for (int i = 0; i < 8; ++i)                                                     \
        _Pragma("unroll")                                                           \
        for (int j = 0; j < 4; ++j) {                                               \
            acc[i][j] = __fadd_rn(acc[i][j], accC[i][j]);                           \
            accC[i][j] = 0.f;                                                       \
        }                                                                           \
} while (0)

    int foldcnt = 6;                                   // fold at k=384 multiples
#pragma unroll 1
    for (int k0 = 0; k0 < K; k0 += 64) {
        // subtile 0: k0 .. k0+31
#pragma unroll
        for (int rr = 0; rr < 4; ++rr)
            __builtin_amdgcn_global_load_lds(AS1(A + aoff[rr] + k0), AS3(As + lba[rr]), 16, 0, 0);
#pragma unroll
        for (int rr = 0; rr < 2; ++rr)
            __builtin_amdgcn_global_load_lds(AS1(B + boff[rr] + k0), AS3(Bs + lbb[rr]), 16, 0, 0);
        // subtile 1: k0+32 .. k0+63
#pragma unroll
        for (int rr = 0; rr < 4; ++rr)
            __builtin_amdgcn_global_load_lds(AS1(A + aoff[rr] + k0 + 32), AS3(As + 4096 + lba[rr]), 16, 0, 0);
#pragma unroll
        for (int rr = 0; rr < 2; ++rr)
            __builtin_amdgcn_global_load_lds(AS1(B + boff[rr] + k0 + 32), AS3(Bs + 2048 + lbb[rr]), 16, 0, 0);
        __syncthreads();

        COMPUTE(As, Bs);                 // k ascending: k0..k0+31
        COMPUTE((As + 4096), (Bs + 2048)); // then k0+32..k0+63
        if (--foldcnt == 0) { FOLD(); foldcnt = 6; }
        __syncthreads();
    }
    FOLD();                                            // K%384=128 remainder

#undef COMPUTE
#undef FOLD

    float bv[4];
#pragma unroll
    for (int j = 0; j < 4; ++j) bv[j] = bias[col0 + tx * 4 + j];
#pragma unroll
    for (int i = 0; i < 8; ++i) {
        size_t r = (size_t)(row0 + ty * 8 + i) * N + col0 + tx * 4;
        float4 o;
        o.x = __fadd_rn(acc[i][0], bv[0]); o.y = __fadd_rn(acc[i][1], bv[1]);
        o.z = __fadd_rn(acc[i][2], bv[2]); o.w = __fadd_rn(acc[i][3], bv[3]);
        *(float4*)(C + r) = o;
    }
}

// ---------------- dist GEMM: 128x128, 8x8, K=128, argmin epilogue ----------------
__global__ __launch_bounds__(256)
void dist_gemm(const float* __restrict__ A, const float* __restrict__ B,
               const float* __restrict__ xsq, const float* __restrict__ esq,
               float* __restrict__ pmin, int* __restrict__ pidx)
{
    constexpr int K = C_DIM;
    __shared__ __align__(128) float As[4096];
    __shared__ __align__(128) float Bs[4096];
    const int tid  = threadIdx.x;
    const int ty   = tid >> 4, tx = tid & 15;
    const int lane = tid & 63, wave = tid >> 6;
    const int row0 = blockIdx.y * 128, col0 = blockIdx.x * 128;

    float acc[8][8];
#pragma unroll
    for (int i = 0; i < 8; ++i)
#pragma unroll
        for (int j = 0; j < 8; ++j) acc[i][j] = 0.f;

    size_t aoff[4], boff[4];
    int lb[4];
#pragma unroll
    for (int rr = 0; rr < 4; ++rr) {
        const int g = wave * 4 + rr;
        const int r = g * 8 + (lane >> 3);
        const int c = (lane & 7) ^ (g & 7);
        aoff[rr] = (size_t)(row0 + r) * K + c * 4;
        boff[rr] = (size_t)(col0 + r) * K + c * 4;
        lb[rr]   = g * 256;
    }

    const int sa = ty & 7, sb = tx & 7;

    for (int k0 = 0; k0 < K; k0 += 32) {
#pragma unroll
        for (int rr = 0; rr < 4; ++rr) {
            __builtin_amdgcn_global_load_lds(AS1(A + aoff[rr] + k0), AS3(As + lb[rr]), 16, 0, 0);
            __builtin_amdgcn_global_load_lds(AS1(B + boff[rr] + k0), AS3(Bs + lb[rr]), 16, 0, 0);
        }
        __syncthreads();

        const char* Ab = (const char*)&As[ty * 8 * 32] + (sa << 4);
        const char* Bb = (const char*)&Bs[tx * 8 * 32] + (sb << 4);
#pragma unroll
        for (int kk = 0; kk < 8; ++kk) {
            const char* ar = (const char*)((uintptr_t)Ab ^ (unsigned)(kk << 4));
            const char* br = (const char*)((uintptr_t)Bb ^ (unsigned)(kk << 4));
            float4 b4[8];
#pragma unroll
            for (int j = 0; j < 8; ++j)
                b4[j] = *(const float4*)(br + j * 128);
#pragma unroll
            for (int i = 0; i < 8; ++i) {
                float4 a4 = *(const float4*)(ar + i * 128);
#pragma unroll
                for (int j = 0; j < 8; ++j) {
                    float t = acc[i][j];
                    t = fmaf(a4.x, b4[j].x, t);
                    t = fmaf(a4.y, b4[j].y, t);
                    t = fmaf(a4.z, b4[j].z, t);
                    t = fmaf(a4.w, b4[j].w, t);
                    acc[i][j] = t;
                }
            }
        }
        __syncthreads();
    }

    float (*rmin)[16] = (float (*)[16])As;
    int   (*ridx)[16] = (int (*)[16])Bs;
    float es[8];
#pragma unroll
    for (int j = 0; j < 8; ++j) es[j] = esq[col0 + tx * 8 + j];
#pragma unroll
    for (int i = 0; i < 8; ++i) {
        float xs = xsq[row0 + ty * 8 + i];
        float b = __fadd_rn(__fsub_rn(xs, __fmul_rn(2.0f, acc[i][0])), es[0]);
        int bi = col0 + tx * 8;
#pragma unroll
        for (int j = 1; j < 8; ++j) {
            float d = __fadd_rn(__fsub_rn(xs, __fmul_rn(2.0f, acc[i][j])), es[j]);
            if (d < b) { b = d; bi = col0 + tx * 8 + j; }
        }
        rmin[ty * 8 + i][tx] = b;
        ridx[ty * 8 + i][tx] = bi;
    }
    __syncthreads();
    if (tid < 128) {
        float b = rmin[tid][0]; int ix = ridx[tid][0];
#pragma unroll
        for (int t = 1; t < 16; ++t) {
            if (rmin[tid][t] < b) { b = rmin[tid][t]; ix = ridx[tid][t]; }
        }
        size_t o = (size_t)(row0 + tid) * gridDim.x + blockIdx.x;
        pmin[o] = b; pidx[o] = ix;
    }
}

// ---------------- merge 4 col-blocks -> final idx + histogram ----------------
__global__ __launch_bounds__(256)
void finalize_idx(const float* __restrict__ pmin, const int* __restrict__ pidx,
                  int* __restrict__ idx_int, float* __restrict__ idx_f,
                  unsigned* __restrict__ counts) {
    __shared__ unsigned hist[NCODES];
    int t = threadIdx.x;
    hist[t] = 0u; hist[t + 256] = 0u;
    __syncthreads();
    int row = blockIdx.x * 256 + t;
    size_t base = (size_t)row * 4;
    float b = pmin[base]; int ix = pidx[base];
#pragma unroll
    for (int nb = 1; nb < 4; ++nb) {
        float v = pmin[base + nb];
        if (v < b) { b = v; ix = pidx[base + nb]; }
    }
    idx_int[row] = ix;
    idx_f[row] = (float)ix;
    atomicAdd(&hist[ix], 1u);
    __syncthreads();
    if (hist[t]) atomicAdd(&counts[t], hist[t]);
    if (hist[t + 256]) atomicAdd(&counts[t + 256], hist[t + 256]);
}

// ---------------- split codebook / dec_w into bf16 hi+lo ----------------
__global__ __launch_bounds__(256)
void split_hi_lo(const float* __restrict__ src, ushort* __restrict__ hi,
                 ushort* __restrict__ lo, int n4) {
    int e = blockIdx.x * 256 + threadIdx.x;
    if (e >= n4) return;
    float4 v = *(const float4*)&src[(size_t)e * 4];
    ushort h0 = f2bf(v.x), h1 = f2bf(v.y), h2 = f2bf(v.z), h3 = f2bf(v.w);
    ushort l0 = f2bf(v.x - bf2f(h0)), l1 = f2bf(v.y - bf2f(h1));
    ushort l2 = f2bf(v.z - bf2f(h2)), l3 = f2bf(v.w - bf2f(h3));
    ushort4 H; H.x = h0; H.y = h1; H.z = h2; H.w = h3;
    ushort4 L; L.x = l0; L.y = l1; L.z = l2; L.w = l3;
    *(ushort4*)&hi[(size_t)e * 4] = H;
    *(ushort4*)&lo[(size_t)e * 4] = L;
}

// ---------------- loss only (reads flat, does NOT modify it) ----------------
__global__ __launch_bounds__(256)
void gather_loss(const float* __restrict__ flat, const int* __restrict__ idx,
                 const float* __restrict__ cb, float* __restrict__ loss_sum) {
    size_t e0 = ((size_t)blockIdx.x * 256 + threadIdx.x) * 8;
    int n = (int)(e0 >> 7);
    int c = (int)(e0 & 127);
    int k = idx[n];
    const float4* qp = (const float4*)(cb + (size_t)k * C_DIM + c);
    float4 q0 = qp[0], q1 = qp[1];
    const float4* fp = (const float4*)(flat + e0);
    float4 f0 = fp[0], f1 = fp[1];
    float s = 0.f, d;
    d = q0.x - f0.x; s += d * d;  d = q0.y - f0.y; s += d * d;
    d = q0.z - f0.z; s += d * d;  d = q0.w - f0.w; s += d * d;
    d = q1.x - f1.x; s += d * d;  d = q1.y - f1.y; s += d * d;
    d = q1.z - f1.z; s += d * d;  d = q1.w - f1.w; s += d * d;

    __shared__ float redf[256];
    redf[threadIdx.x] = s;
    __syncthreads();
    for (int st = 128; st; st >>= 1) {
        if (threadIdx.x < st) redf[threadIdx.x] += redf[threadIdx.x + st];
        __syncthreads();
    }
    if (threadIdx.x == 0) atomicAdd(loss_sum, redf[0]);
}

// ---------------- gather split-bf16 quantized rows ----------------
__global__ __launch_bounds__(256)
void build_q(const int* __restrict__ idx, const ushort* __restrict__ cbh,
             const ushort* __restrict__ cbl, ushort* __restrict__ Qh,
             ushort* __restrict__ Ql) {
    int t = blockIdx.x * 256 + threadIdx.x;   // 16B chunk id
    int n = t >> 4, c8 = t & 15;
    int k = idx[n];
    uint4 vh = *(const uint4*)&cbh[(size_t)k * C_DIM + c8 * 8];
    uint4 vl = *(const uint4*)&cbl[(size_t)k * C_DIM + c8 * 8];
    *(uint4*)&Qh[(size_t)n * C_DIM + c8 * 8] = vh;
    *(uint4*)&Ql[(size_t)n * C_DIM + c8 * 8] = vl;
}

// ---------------- decoder: split-bf16 MFMA GEMM, XCD-swizzled 1-D grid ----------------
__global__ __launch_bounds__(256)
void dec_gemm_bf16(const ushort* __restrict__ Qh, const ushort* __restrict__ Ql,
                   const ushort* __restrict__ Wh, const ushort* __restrict__ Wl,
                   const float* __restrict__ bias, float* __restrict__ C)
{
    constexpr int Kd = 512, Nd = 2048;
    __shared__ ushort Ah[128 * 32], Al[128 * 32], Bh[128 * 32], Bl[128 * 32];
    const int gid = blockIdx.x;                       // 4096 blocks
    const int f   = (gid & 7) * 512 + (gid >> 3);
    const int bx  = f & 15, by = f >> 4;
    const int tid  = threadIdx.x;
    const int lane = tid & 63, wave = tid >> 6;
    const int wm = wave >> 1, wn = wave & 1;
    const int row0 = by * 128, col0 = bx * 128;

    f32x4 acc[4][4];
#pragma unroll
    for (int i = 0; i < 4; ++i)
#pragma unroll
        for (int j = 0; j < 4; ++j)
#pragma unroll
            for (int q = 0; q < 4; ++q) acc[i][j][q] = 0.f;

    const int fr = lane & 15, s4 = lane >> 4;

    for (int kt = 0; kt < Kd / 32; ++kt) {
        const int k0 = kt * 32;
#pragma unroll
        for (int r = 0; r < 2; ++r) {
            const int t2 = r * 256 + wave * 64 + lane;
            const int ro = t2 >> 2, sb = t2 & 3;
            const int base = (r * 256 + wave * 64) * 8;
            const size_t ga = (size_t)(row0 + ro) * Kd + k0 + sb * 8;
            const size_t gb = (size_t)(col0 + ro) * Kd + k0 + sb * 8;
            __builtin_amdgcn_global_load_lds(AS1(Qh + ga), AS3(&Ah[base]), 16, 0, 0);
            __builtin_amdgcn_global_load_lds(AS1(Ql + ga), AS3(&Al[base]), 16, 0, 0);
            __builtin_amdgcn_global_load_lds(AS1(Wh + gb), AS3(&Bh[base]), 16, 0, 0);
            __builtin_amdgcn_global_load_lds(AS1(Wl + gb), AS3(&Bl[base]), 16, 0, 0);
        }
        __syncthreads();

        bf16x8 ah[4], al[4], bh[4], bl[4];
#pragma unroll
        for (int mi = 0; mi < 4; ++mi) {
            const int off = (wm * 64 + mi * 16 + fr) * 32 + s4 * 8;
            ah[mi] = *(const bf16x8*)&Ah[off];
            al[mi] = *(const bf16x8*)&Al[off];
        }
#pragma unroll
        for (int ni = 0; ni < 4; ++ni) {
            const int off = (wn * 64 + ni * 16 + fr) * 32 + s4 * 8;
            bh[ni] = *(const bf16x8*)&Bh[off];
            bl[ni] = *(const bf16x8*)&Bl[off];
        }
#pragma unroll
        for (int mi = 0; mi < 4; ++mi)
#pragma unroll
            for (int ni = 0; ni < 4; ++ni) {
                acc[mi][ni] = __builtin_amdgcn_mfma_f32_16x16x32_bf16(ah[mi], bh[ni], acc[mi][ni], 0, 0, 0);
                acc[mi][ni] = __builtin_amdgcn_mfma_f32_16x16x32_bf16(ah[mi], bl[ni], acc[mi][ni], 0, 0, 0);
                acc[mi][ni] = __builtin_amdgcn_mfma_f32_16x16x32_bf16(al[mi], bh[ni], acc[mi][ni], 0, 0, 0);
            }
        __syncthreads();
    }

#pragma unroll
    for (int ni = 0; ni < 4; ++ni) {
        const int c = col0 + wn * 64 + ni * 16 + fr;
        const float bv = bias[c];
#pragma unroll
        for (int mi = 0; mi < 4; ++mi) {
            const int r = row0 + wm * 64 + mi * 16 + s4 * 4;
#pragma unroll
            for (int q = 0; q < 4; ++q)
                C[(size_t)(r + q) * Nd + c] = acc[mi][ni][q] + bv;
        }
    }
}

// ---------------- scalars ----------------
__global__ __launch_bounds__(512)
void finalize_scalars(const unsigned* __restrict__ counts,
                      const float* __restrict__ loss_sum, float* __restrict__ out5) {
    __shared__ float rent[512];
    __shared__ float ruse[512];
    int t = threadIdx.x;
    float c = (float)counts[t];
    float avg = c * (1.0f / (float)NROWS);
    rent[t] = avg * logf(avg + 1e-10f);
    ruse[t] = counts[t] > 0u ? 1.f : 0.f;
    __syncthreads();
    for (int st = 256; st; st >>= 1) {
        if (t < st) { rent[t] += rent[t + st]; ruse[t] += ruse[t + st]; }
        __syncthreads();
    }
    if (t == 0) {
        float H = -rent[0];
        float perp = expf(H);
        float cl = loss_sum[0] * (1.0f / (float)NELEM);
        out5[0] = cl + 0.25f * cl;
        out5[1] = cl;
        out5[2] = cl;
        out5[3] = perp;
        out5[4] = ruse[0] * (1.0f / (float)NCODES);
    }
}

extern "C" void kernel_launch(void* const* d_in, const int* in_sizes, int n_in,
                              void* d_out, int out_size, void* d_ws, size_t ws_size,
                              hipStream_t stream) {
    const float* h     = (const float*)d_in[0];
    const float* enc_w = (const float*)d_in[1];
    const float* enc_b = (const float*)d_in[2];
    const float* cb    = (const float*)d_in[3];
    const float* dec_w = (const float*)d_in[4];
    const float* dec_b = (const float*)d_in[5];
    float* out = (float*)d_out;

    float* ws = (float*)d_ws;
    float*    flat     = ws;                         // [0, 16777216)
    float*    xsq      = ws + 16777216;              // 131072 (dead after dist)
    float*    pmin     = ws + 16908288;              // 524288 (dead after finalize)
    int*      pidx     = (int*)(ws + 17432576);      // 524288 (dead after finalize)
    int*      idx_int  = (int*)(ws + 17956864);      // 131072
    float*    esq      = ws + 18087936;              // 512
    unsigned* counts   = (unsigned*)(ws + 18088448); // 512
    float*    loss_sum = ws + 18088960;              // 1

    // overlays (used only after their hosts are dead):
    ushort* Qh  = (ushort*)ws;                       // over flat
    ushort* Ql  = (ushort*)(ws + 8388608);           // over flat
    ushort* cbh = (ushort*)(ws + 16777216);          // over xsq
    ushort* cbl = (ushort*)(ws + 16809984);          // over xsq
    ushort* Wh  = (ushort*)(ws + 16842752);          // over xsq/pmin
    ushort* Wl  = (ushort*)(ws + 17367040);          // over pmin/pidx

    float* msg_out = out;                     // 67108864
    float* idx_out = out + 67108864;          // 131072
    float* sc_out  = out + 67108864 + 131072; // 5

    zero_kernel<<<1, 512, 0, stream>>>(counts, loss_sum);
    sq_pairwise<<<NCODES / 32, 256, 0, stream>>>(cb, esq, NCODES);

    // encoder: flat = h @ enc_w^T + enc_b (numpy kc=384 folds), BK=64
    enc_gemm<<<2048, 256, 0, stream>>>(h, enc_w, enc_b, flat);

    sq_pairwise<<<NROWS / 32, 256, 0, stream>>>(flat, xsq, NROWS);

    // distances + per-colblock argmin
    dist_gemm<<<dim3(NCODES / 128, NROWS / 128), 256, 0, stream>>>(
        flat, cb, xsq, esq, pmin, pidx);

    finalize_idx<<<NROWS / 256, 256, 0, stream>>>(pmin, pidx, idx_int, idx_out, counts);

    // xsq/pmin/pidx now dead -> build bf16 splits in their space
    split_hi_lo<<<(NCODES * C_DIM / 4 + 255) / 256, 256, 0, stream>>>(cb, cbh, cbl, NCODES * C_DIM / 4);
    split_hi_lo<<<(D_DIM * KC_DIM / 4 + 255) / 256, 256, 0, stream>>>(dec_w, Wh, Wl, D_DIM * KC_DIM / 4);

    gather_loss<<<NELEM / (256 * 8), 256, 0, stream>>>(flat, idx_int, cb, loss_sum);

    // flat now dead -> gather split-bf16 quantized rows into its space
    build_q<<<NROWS * 16 / 256, 256, 0, stream>>>(idx_int, cbh, cbl, Qh, Ql);

    // decoder on matrix cores, XCD-swizzled
    dec_gemm_bf16<<<4096, 256, 0, stream>>>(Qh, Ql, Wh, Wl, dec_b, msg_out);

    finalize_scalars<<<1, 512, 0, stream>>>(counts, loss_sum, sc_out);
}

// Round 11
// 1993.366 us; speedup vs baseline: 1.1716x; 1.0729x over previous
//
#include <hip/hip_runtime.h>
#include <hip/hip_bf16.h>

// B=16, T=2048, D=2048, K(msg)=4, C=128, KC=512, CODEBOOK=512
#define M_BT      32768
#define KC_DIM    512
#define D_DIM     2048
#define C_DIM     128
#define NROWS     131072
#define NCODES    512
#define NELEM     16777216   // NROWS*C_DIM
#define GAP_EPS   4.0e-3f
#define FLT_BIG   3.4028235e38f

typedef __bf16 bf16x8 __attribute__((ext_vector_type(8)));
typedef float  f32x4  __attribute__((ext_vector_type(4)));

#define AS3(p) ((__attribute__((address_space(3))) void*)(p))
#define AS1(p) ((const __attribute__((address_space(1))) void*)(p))

static __device__ __forceinline__ ushort f2bf(float x) {
    unsigned u = __float_as_uint(x);
    unsigned r = (u + 0x7fffu + ((u >> 16) & 1u)) >> 16;
    return (ushort)r;
}
static __device__ __forceinline__ float bf2f(ushort u) {
    return __uint_as_float(((unsigned)u) << 16);
}

// ---------------- zero counters ----------------
__global__ __launch_bounds__(512)
void zero_kernel(unsigned* __restrict__ counts, float* __restrict__ loss_sum,
                 int* __restrict__ nflag) {
    counts[threadIdx.x] = 0u;
    if (threadIdx.x == 0) { loss_sum[0] = 0.f; nflag[0] = 0; }
}

// ---------------- numpy-pairwise sum of squares per 128-row ----------------
__global__ __launch_bounds__(256)
void sq_pairwise(const float* __restrict__ src, float* __restrict__ dst, int nrows) {
    int t = threadIdx.x;
    int row = blockIdx.x * 32 + (t >> 3);
    int j = t & 7;
    if (row >= nrows) return;
    const float* p = src + (size_t)row * C_DIM + j;
    float v = p[0];
    float r = __fmul_rn(v, v);
#pragma unroll
    for (int i = 1; i < 16; ++i) {
        float u = p[i * 8];
        r = __fadd_rn(r, __fmul_rn(u, u));
    }
    r = __fadd_rn(r, __shfl_xor(r, 1));
    r = __fadd_rn(r, __shfl_xor(r, 2));
    r = __fadd_rn(r, __shfl_xor(r, 4));
    if (j == 0) dst[row] = r;
}

// ---------------- split fp32 matrix into bf16 hi+lo ----------------
__global__ __launch_bounds__(256)
void split_hi_lo(const float* __restrict__ src, ushort* __restrict__ hi,
                 ushort* __restrict__ lo, int n4) {
    int e = blockIdx.x * 256 + threadIdx.x;
    if (e >= n4) return;
    float4 v = *(const float4*)&src[(size_t)e * 4];
    ushort h0 = f2bf(v.x), h1 = f2bf(v.y), h2 = f2bf(v.z), h3 = f2bf(v.w);
    ushort l0 = f2bf(v.x - bf2f(h0)), l1 = f2bf(v.y - bf2f(h1));
    ushort l2 = f2bf(v.z - bf2f(h2)), l3 = f2bf(v.w - bf2f(h3));
    ushort4 H; H.x = h0; H.y = h1; H.z = h2; H.w = h3;
    ushort4 L; L.x = l0; L.y = l1; L.z = l2; L.w = l3;
    *(ushort4*)&hi[(size_t)e * 4] = H;
    *(ushort4*)&lo[(size_t)e * 4] = L;
}

// ---------------- encoder: split-bf16 MFMA GEMM (approximate) ----------------
// flat ~= h @ enc_w^T + enc_b  (hh+hl+lh products; ll dropped, err ~1e-5).
// h converted to bf16 hi/lo on the fly (reg->LDS); EW pre-split, global_load_lds.
__global__ __launch_bounds__(256)
void enc_mfma(const float* __restrict__ h, const ushort* __restrict__ EWh,
              const ushort* __restrict__ EWl, const float* __restrict__ bias,
              float* __restrict__ C)
{
    constexpr int K = D_DIM, N = KC_DIM;
    __shared__ ushort Ah[128 * 32], Al[128 * 32], Bh[128 * 32], Bl[128 * 32];
    const int gid = blockIdx.x;                 // 1024 blocks
    const int f   = (gid & 7) * 128 + (gid >> 3);
    const int bx  = f & 3, by = f >> 2;         // 4 col-blocks, 256 row-blocks
    const int row0 = by * 128, col0 = bx * 128;
    const int tid  = threadIdx.x;
    const int lane = tid & 63, wave = tid >> 6;
    const int wm = wave >> 1, wn = wave & 1;

    f32x4 acc[4][4];
#pragma unroll
    for (int i = 0; i < 4; ++i)
#pragma unroll
        for (int j = 0; j < 4; ++j)
#pragma unroll
            for (int q = 0; q < 4; ++q) acc[i][j][q] = 0.f;

    const int fr = lane & 15, s4 = lane >> 4;
    const int arow = tid >> 3, ak8 = tid & 7;    // A-convert: rows tid>>3 + q*32

    for (int kt = 0; kt < K / 32; ++kt) {
        const int k0 = kt * 32;
        // B staging (pre-split bf16) via global_load_lds
#pragma unroll
        for (int r = 0; r < 2; ++r) {
            const int t2 = r * 256 + wave * 64 + lane;
            const int ro = t2 >> 2, sb = t2 & 3;
            const int base = (r * 256 + wave * 64) * 8;
            const size_t gb = (size_t)(col0 + ro) * K + k0 + sb * 8;
            __builtin_amdgcn_global_load_lds(AS1(EWh + gb), AS3(&Bh[base]), 16, 0, 0);
            __builtin_amdgcn_global_load_lds(AS1(EWl + gb), AS3(&Bl[base]), 16, 0, 0);
        }
        // A staging: load fp32 h, convert to hi/lo, ds_write
#pragma unroll
        for (int q = 0; q < 4; ++q) {
            const int row = q * 32 + arow;
            float4 v = *(const float4*)&h[(size_t)(row0 + row) * K + k0 + ak8 * 4];
            ushort h0 = f2bf(v.x), h1 = f2bf(v.y), h2 = f2bf(v.z), h3 = f2bf(v.w);
            ushort l0 = f2bf(v.x - bf2f(h0)), l1 = f2bf(v.y - bf2f(h1));
            ushort l2 = f2bf(v.z - bf2f(h2)), l3 = f2bf(v.w - bf2f(h3));
            ushort4 H; H.x = h0; H.y = h1; H.z = h2; H.w = h3;
            ushort4 L; L.x = l0; L.y = l1; L.z = l2; L.w = l3;
            *(ushort4*)&Ah[row * 32 + ak8 * 4] = H;
            *(ushort4*)&Al[row * 32 + ak8 * 4] = L;
        }
        __syncthreads();

        bf16x8 ah[4], al[4], bh[4], bl[4];
#pragma unroll
        for (int mi = 0; mi < 4; ++mi) {
            const int off = (wm * 64 + mi * 16 + fr) * 32 + s4 * 8;
            ah[mi] = *(const bf16x8*)&Ah[off];
            al[mi] = *(const bf16x8*)&Al[off];
        }
#pragma unroll
        for (int ni = 0; ni < 4; ++ni) {
            const int off = (wn * 64 + ni * 16 + fr) * 32 + s4 * 8;
            bh[ni] = *(const bf16x8*)&Bh[off];
            bl[ni] = *(const bf16x8*)&Bl[off];
        }
#pragma unroll
        for (int mi = 0; mi < 4; ++mi)
#pragma unroll
            for (int ni = 0; ni < 4; ++ni) {
                acc[mi][ni] = __builtin_amdgcn_mfma_f32_16x16x32_bf16(ah[mi], bh[ni], acc[mi][ni], 0, 0, 0);
                acc[mi][ni] = __builtin_amdgcn_mfma_f32_16x16x32_bf16(ah[mi], bl[ni], acc[mi][ni], 0, 0, 0);
                acc[mi][ni] = __builtin_amdgcn_mfma_f32_16x16x32_bf16(al[mi], bh[ni], acc[mi][ni], 0, 0, 0);
            }
        __syncthreads();
    }

#pragma unroll
    for (int ni = 0; ni < 4; ++ni) {
        const int c = col0 + wn * 64 + ni * 16 + fr;
        const float bv = bias[c];
#pragma unroll
        for (int mi = 0; mi < 4; ++mi) {
            const int r = row0 + wm * 64 + mi * 16 + s4 * 4;
#pragma unroll
            for (int q = 0; q < 4; ++q)
                C[(size_t)(r + q) * N + c] = acc[mi][ni][q] + bv;
        }
    }
}

// ---------------- dist GEMM: 128x128, 8x8, K=128, best+second epilogue ----------
__global__ __launch_bounds__(256)
void dist_gemm(const float* __restrict__ A, const float* __restrict__ B,
               const float* __restrict__ xsq, const float* __restrict__ esq,
               float* __restrict__ pmin, float* __restrict__ psec,
               int* __restrict__ pidx)
{
    constexpr int K = C_DIM;
    __shared__ __align__(128) float As[4096];
    __shared__ __align__(128) float Bs[4096];
    const int tid  = threadIdx.x;
    const int ty   = tid >> 4, tx = tid & 15;
    const int lane = tid & 63, wave = tid >> 6;
    const int row0 = blockIdx.y * 128, col0 = blockIdx.x * 128;

    float acc[8][8];
#pragma unroll
    for (int i = 0; i < 8; ++i)
#pragma unroll
        for (int j = 0; j < 8; ++j) acc[i][j] = 0.f;

    size_t aoff[4], boff[4];
    int lb[4];
#pragma unroll
    for (int rr = 0; rr < 4; ++rr) {
        const int g = wave * 4 + rr;
        const int r = g * 8 + (lane >> 3);
        const int c = (lane & 7) ^ (g & 7);
        aoff[rr] = (size_t)(row0 + r) * K + c * 4;
        boff[rr] = (size_t)(col0 + r) * K + c * 4;
        lb[rr]   = g * 256;
    }

    const int sa = ty & 7, sb = tx & 7;

    for (int k0 = 0; k0 < K; k0 += 32) {
#pragma unroll
        for (int rr = 0; rr < 4; ++rr) {
            __builtin_amdgcn_global_load_lds(AS1(A + aoff[rr] + k0), AS3(As + lb[rr]), 16, 0, 0);
            __builtin_amdgcn_global_load_lds(AS1(B + boff[rr] + k0), AS3(Bs + lb[rr]), 16, 0, 0);
        }
        __syncthreads();

        const char* Ab = (const char*)&As[ty * 8 * 32] + (sa << 4);
        const char* Bb = (const char*)&Bs[tx * 8 * 32] + (sb << 4);
#pragma unroll
        for (int kk = 0; kk < 8; ++kk) {
            const char* ar = (const char*)((uintptr_t)Ab ^ (unsigned)(kk << 4));
            const char* br = (const char*)((uintptr_t)Bb ^ (unsigned)(kk << 4));
            float4 b4[8];
#pragma unroll
            for (int j = 0; j < 8; ++j)
                b4[j] = *(const float4*)(br + j * 128);
#pragma unroll
            for (int i = 0; i < 8; ++i) {
                float4 a4 = *(const float4*)(ar + i * 128);
#pragma unroll
                for (int j = 0; j < 8; ++j) {
                    float t = acc[i][j];
                    t = fmaf(a4.x, b4[j].x, t);
                    t = fmaf(a4.y, b4[j].y, t);
                    t = fmaf(a4.z, b4[j].z, t);
                    t = fmaf(a4.w, b4[j].w, t);
                    acc[i][j] = t;
                }
            }
        }
        __syncthreads();
    }

    float (*rmin)[16] = (float (*)[16])As;
    float (*rsec)[16] = (float (*)[16])(As + 2048);
    int   (*ridx)[16] = (int   (*)[16])Bs;
    float es[8];
#pragma unroll
    for (int j = 0; j < 8; ++j) es[j] = esq[col0 + tx * 8 + j];
#pragma unroll
    for (int i = 0; i < 8; ++i) {
        float xs = xsq[row0 + ty * 8 + i];
        float b = __fadd_rn(__fsub_rn(xs, __fmul_rn(2.0f, acc[i][0])), es[0]);
        int bi = col0 + tx * 8;
        float sde = FLT_BIG;
#pragma unroll
        for (int j = 1; j < 8; ++j) {
            float d = __fadd_rn(__fsub_rn(xs, __fmul_rn(2.0f, acc[i][j])), es[j]);
            if (d < b) { sde = b; b = d; bi = col0 + tx * 8 + j; }
            else       { sde = fminf(sde, d); }
        }
        rmin[ty * 8 + i][tx] = b;
        rsec[ty * 8 + i][tx] = sde;
        ridx[ty * 8 + i][tx] = bi;
    }
    __syncthreads();
    if (tid < 128) {
        float b = rmin[tid][0], sde = rsec[tid][0]; int ix = ridx[tid][0];
#pragma unroll
        for (int t = 1; t < 16; ++t) {
            float b2 = rmin[tid][t], s2 = rsec[tid][t];
            if (b2 < b) { sde = fminf(b, s2); b = b2; ix = ridx[tid][t]; }
            else        { sde = fminf(sde, b2); }
        }
        size_t o = (size_t)(row0 + tid) * gridDim.x + blockIdx.x;
        pmin[o] = b; psec[o] = sde; pidx[o] = ix;
    }
}

// ---------------- merge 4 col-blocks -> idx + near-tie flags ----------------
__global__ __launch_bounds__(256)
void merge_flag(const float* __restrict__ pmin, const float* __restrict__ psec,
                const int* __restrict__ pidx, int* __restrict__ idx_int,
                float* __restrict__ idx_f, int* __restrict__ rowlist,
                int* __restrict__ nflag) {
    int row = blockIdx.x * 256 + threadIdx.x;
    size_t base = (size_t)row * 4;
    float b = pmin[base], sde = psec[base]; int ix = pidx[base];
#pragma unroll
    for (int nb = 1; nb < 4; ++nb) {
        float b2 = pmin[base + nb], s2 = psec[base + nb];
        if (b2 < b) { sde = fminf(b, s2); b = b2; ix = pidx[base + nb]; }
        else        { sde = fminf(sde, b2); }
    }
    idx_int[row] = ix;
    idx_f[row] = (float)ix;
    if (sde - b < GAP_EPS) {
        int p = atomicAdd(nflag, 1);
        rowlist[p] = row;
    }
}

// ---------------- exact recompute of near-tie rows (numpy-bit-exact) ----------
__global__ __launch_bounds__(256)
void refine_rows(const float* __restrict__ h, const float* __restrict__ enc_w,
                 const float* __restrict__ enc_b, const float* __restrict__ cb,
                 const float* __restrict__ esq, const int* __restrict__ rowlist,
                 const int* __restrict__ nflag_p, int* __restrict__ idx_int,
                 float* __restrict__ idx_f)
{
    __shared__ __align__(16) float x[C_DIM];
    __shared__ float xs_sh;
    __shared__ float rb[256];
    __shared__ int   ri[256];
    const int tid = threadIdx.x;
    const int nf = *nflag_p;
    for (int fi = blockIdx.x; fi < nf; fi += gridDim.x) {
        const int row = rowlist[fi];
        const int bt = row >> 2, seg = row & 3;
        // exact encoder element (sequential k, kc=384 folds) — one thread/element
        if (tid < C_DIM) {
            const float* hp = h + (size_t)bt * D_DIM;
            const float* wp = enc_w + (size_t)(seg * C_DIM + tid) * D_DIM;
            float acc = 0.f, accC = 0.f;
            int fold = 96;   // 384/4
#pragma unroll 1
            for (int d = 0; d < D_DIM; d += 4) {
                float4 hv = *(const float4*)(hp + d);
                float4 wv = *(const float4*)(wp + d);
                accC = fmaf(hv.x, wv.x, accC);
                accC = fmaf(hv.y, wv.y, accC);
                accC = fmaf(hv.z, wv.z, accC);
                accC = fmaf(hv.w, wv.w, accC);
                if (--fold == 0) { acc = __fadd_rn(acc, accC); accC = 0.f; fold = 96; }
            }
            acc = __fadd_rn(acc, accC);   // K%384=128 remainder
            x[tid] = __fadd_rn(acc, enc_b[seg * C_DIM + tid]);
        }
        __syncthreads();
        // exact x_sq: numpy pairwise-8 bracket
        if (tid == 0) {
            float rj[8];
#pragma unroll
            for (int j = 0; j < 8; ++j) rj[j] = __fmul_rn(x[j], x[j]);
            for (int i = 1; i < 16; ++i)
#pragma unroll
                for (int j = 0; j < 8; ++j)
                    rj[j] = __fadd_rn(rj[j], __fmul_rn(x[i * 8 + j], x[i * 8 + j]));
            float a01 = __fadd_rn(rj[0], rj[1]);
            float a23 = __fadd_rn(rj[2], rj[3]);
            float a45 = __fadd_rn(rj[4], rj[5]);
            float a67 = __fadd_rn(rj[6], rj[7]);
            xs_sh = __fadd_rn(__fadd_rn(a01, a23), __fadd_rn(a45, a67));
        }
        __syncthreads();
        const float xs = xs_sh;
        // exact dists: thread t -> codes 2t, 2t+1 (sequential fmaf over c)
        float best; int bi;
        {
            const int c0 = tid * 2;
            const float* e0 = cb + (size_t)c0 * C_DIM;
            float dot0 = 0.f, dot1 = 0.f;
#pragma unroll 1
            for (int c = 0; c < C_DIM; c += 4) {
                float4 xv  = *(const float4*)&x[c];
                float4 ev0 = *(const float4*)(e0 + c);
                float4 ev1 = *(const float4*)(e0 + C_DIM + c);
                dot0 = fmaf(xv.x, ev0.x, dot0); dot0 = fmaf(xv.y, ev0.y, dot0);
                dot0 = fmaf(xv.z, ev0.z, dot0); dot0 = fmaf(xv.w, ev0.w, dot0);
                dot1 = fmaf(xv.x, ev1.x, dot1); dot1 = fmaf(xv.y, ev1.y, dot1);
                dot1 = fmaf(xv.z, ev1.z, dot1); dot1 = fmaf(xv.w, ev1.w, dot1);
            }
            float d0 = __fadd_rn(__fsub_rn(xs, __fmul_rn(2.0f, dot0)), esq[c0]);
            float d1 = __fadd_rn(__fsub_rn(xs, __fmul_rn(2.0f, dot1)), esq[c0 + 1]);
            if (d1 < d0) { best = d1; bi = c0 + 1; } else { best = d0; bi = c0; }
        }
        rb[tid] = best; ri[tid] = bi;
        __syncthreads();
        for (int st = 128; st; st >>= 1) {
            if (tid < st) {
                float d2 = rb[tid + st]; int i2 = ri[tid + st];
                if (d2 < rb[tid] || (d2 == rb[tid] && i2 < ri[tid])) {
                    rb[tid] = d2; ri[tid] = i2;
                }
            }
            __syncthreads();
        }
        if (tid == 0) { idx_int[row] = ri[0]; idx_f[row] = (float)ri[0]; }
        __syncthreads();
    }
}

// ---------------- histogram over final indices ----------------
__global__ __launch_bounds__(256)
void histogram_kernel(const int* __restrict__ idx_int, unsigned* __restrict__ counts) {
    __shared__ unsigned hist[NCODES];
    int t = threadIdx.x;
    hist[t] = 0u; hist[t + 256] = 0u;
    __syncthreads();
    int row = blockIdx.x * 256 + t;
    atomicAdd(&hist[idx_int[row]], 1u);
    __syncthreads();
    if (hist[t]) atomicAdd(&counts[t], hist[t]);
    if (hist[t + 256]) atomicAdd(&counts[t + 256], hist[t + 256]);
}

// ---------------- loss only (reads flat, does NOT modify it) ----------------
__global__ __launch_bounds__(256)
void gather_loss(const float* __restrict__ flat, const int* __restrict__ idx,
                 const float* __restrict__ cb, float* __restrict__ loss_sum) {
    size_t e0 = ((size_t)blockIdx.x * 256 + threadIdx.x) * 8;
    int n = (int)(e0 >> 7);
    int c = (int)(e0 & 127);
    int k = idx[n];
    const float4* qp = (const float4*)(cb + (size_t)k * C_DIM + c);
    float4 q0 = qp[0], q1 = qp[1];
    const float4* fp = (const float4*)(flat + e0);
    float4 f0 = fp[0], f1 = fp[1];
    float s = 0.f, d;
    d = q0.x - f0.x; s += d * d;  d = q0.y - f0.y; s += d * d;
    d = q0.z - f0.z; s += d * d;  d = q0.w - f0.w; s += d * d;
    d = q1.x - f1.x; s += d * d;  d = q1.y - f1.y; s += d * d;
    d = q1.z - f1.z; s += d * d;  d = q1.w - f1.w; s += d * d;

    __shared__ float redf[256];
    redf[threadIdx.x] = s;
    __syncthreads();
    for (int st = 128; st; st >>= 1) {
        if (threadIdx.x < st) redf[threadIdx.x] += redf[threadIdx.x + st];
        __syncthreads();
    }
    if (threadIdx.x == 0) atomicAdd(loss_sum, redf[0]);
}

// ---------------- gather split-bf16 quantized rows ----------------
__global__ __launch_bounds__(256)
void build_q(const int* __restrict__ idx, const ushort* __restrict__ cbh,
             const ushort* __restrict__ cbl, ushort* __restrict__ Qh,
             ushort* __restrict__ Ql) {
    int t = blockIdx.x * 256 + threadIdx.x;   // 16B chunk id
    int n = t >> 4, c8 = t & 15;
    int k = idx[n];
    uint4 vh = *(const uint4*)&cbh[(size_t)k * C_DIM + c8 * 8];
    uint4 vl = *(const uint4*)&cbl[(size_t)k * C_DIM + c8 * 8];
    *(uint4*)&Qh[(size_t)n * C_DIM + c8 * 8] = vh;
    *(uint4*)&Ql[(size_t)n * C_DIM + c8 * 8] = vl;
}

// ---------------- decoder: split-bf16 MFMA GEMM, XCD-swizzled 1-D grid ----------------
__global__ __launch_bounds__(256)
void dec_gemm_bf16(const ushort* __restrict__ Qh, const ushort* __restrict__ Ql,
                   const ushort* __restrict__ Wh, const ushort* __restrict__ Wl,
                   const float* __restrict__ bias, float* __restrict__ C)
{
    constexpr int Kd = 512, Nd = 2048;
    __shared__ ushort Ah[128 * 32], Al[128 * 32], Bh[128 * 32], Bl[128 * 32];
    const int gid = blockIdx.x;                       // 4096 blocks
    const int f   = (gid & 7) * 512 + (gid >> 3);
    const int bx  = f & 15, by = f >> 4;
    const int tid  = threadIdx.x;
    const int lane = tid & 63, wave = tid >> 6;
    const int wm = wave >> 1, wn = wave & 1;
    const int row0 = by * 128, col0 = bx * 128;

    f32x4 acc[4][4];
#pragma unroll
    for (int i = 0; i < 4; ++i)
#pragma unroll
        for (int j = 0; j < 4; ++j)
#pragma unroll
            for (int q = 0; q < 4; ++q) acc[i][j][q] = 0.f;

    const int fr = lane & 15, s4 = lane >> 4;

    for (int kt = 0; kt < Kd / 32; ++kt) {
        const int k0 = kt * 32;
#pragma unroll
        for (int r = 0; r < 2; ++r) {
            const int t2 = r * 256 + wave * 64 + lane;
            const int ro = t2 >> 2, sb = t2 & 3;
            const int base = (r * 256 + wave * 64) * 8;
            const size_t ga = (size_t)(row0 + ro) * Kd + k0 + sb * 8;
            const size_t gb = (size_t)(col0 + ro) * Kd + k0 + sb * 8;
            __builtin_amdgcn_global_load_lds(AS1(Qh + ga), AS3(&Ah[base]), 16, 0, 0);
            __builtin_amdgcn_global_load_lds(AS1(Ql + ga), AS3(&Al[base]), 16, 0, 0);
            __builtin_amdgcn_global_load_lds(AS1(Wh + gb), AS3(&Bh[base]), 16, 0, 0);
            __builtin_amdgcn_global_load_lds(AS1(Wl + gb), AS3(&Bl[base]), 16, 0, 0);
        }
        __syncthreads();

        bf16x8 ah[4], al[4], bh[4], bl[4];
#pragma unroll
        for (int mi = 0; mi < 4; ++mi) {
            const int off = (wm * 64 + mi * 16 + fr) * 32 + s4 * 8;
            ah[mi] = *(const bf16x8*)&Ah[off];
            al[mi] = *(const bf16x8*)&Al[off];
        }
#pragma unroll
        for (int ni = 0; ni < 4; ++ni) {
            const int off = (wn * 64 + ni * 16 + fr) * 32 + s4 * 8;
            bh[ni] = *(const bf16x8*)&Bh[off];
            bl[ni] = *(const bf16x8*)&Bl[off];
        }
#pragma unroll
        for (int mi = 0; mi < 4; ++mi)
#pragma unroll
            for (int ni = 0; ni < 4; ++ni) {
                acc[mi][ni] = __builtin_amdgcn_mfma_f32_16x16x32_bf16(ah[mi], bh[ni], acc[mi][ni], 0, 0, 0);
                acc[mi][ni] = __builtin_amdgcn_mfma_f32_16x16x32_bf16(ah[mi], bl[ni], acc[mi][ni], 0, 0, 0);
                acc[mi][ni] = __builtin_amdgcn_mfma_f32_16x16x32_bf16(al[mi], bh[ni], acc[mi][ni], 0, 0, 0);
            }
        __syncthreads();
    }

#pragma unroll
    for (int ni = 0; ni < 4; ++ni) {
        const int c = col0 + wn * 64 + ni * 16 + fr;
        const float bv = bias[c];
#pragma unroll
        for (int mi = 0; mi < 4; ++mi) {
            const int r = row0 + wm * 64 + mi * 16 + s4 * 4;
#pragma unroll
            for (int q = 0; q < 4; ++q)
                C[(size_t)(r + q) * Nd + c] = acc[mi][ni][q] + bv;
        }
    }
}

// ---------------- scalars ----------------
__global__ __launch_bounds__(512)
void finalize_scalars(const unsigned* __restrict__ counts,
                      const float* __restrict__ loss_sum, float* __restrict__ out5) {
    __shared__ float rent[512];
    __shared__ float ruse[512];
    int t = threadIdx.x;
    float c = (float)counts[t];
    float avg = c * (1.0f / (float)NROWS);
    rent[t] = avg * logf(avg + 1e-10f);
    ruse[t] = counts[t] > 0u ? 1.f : 0.f;
    __syncthreads();
    for (int st = 256; st; st >>= 1) {
        if (t < st) { rent[t] += rent[t + st]; ruse[t] += ruse[t + st]; }
        __syncthreads();
    }
    if (t == 0) {
        float H = -rent[0];
        float perp = expf(H);
        float cl = loss_sum[0] * (1.0f / (float)NELEM);
        out5[0] = cl + 0.25f * cl;
        out5[1] = cl;
        out5[2] = cl;
        out5[3] = perp;
        out5[4] = ruse[0] * (1.0f / (float)NCODES);
    }
}

extern "C" void kernel_launch(void* const* d_in, const int* in_sizes, int n_in,
                              void* d_out, int out_size, void* d_ws, size_t ws_size,
                              hipStream_t stream) {
    const float* h     = (const float*)d_in[0];
    const float* enc_w = (const float*)d_in[1];
    const float* enc_b = (const float*)d_in[2];
    const float* cb    = (const float*)d_in[3];
    const float* dec_w = (const float*)d_in[4];
    const float* dec_b = (const float*)d_in[5];
    float* out = (float*)d_out;

    float* ws = (float*)d_ws;
    float*    flat     = ws;                         // [0, 16777216)
    float*    xsq      = ws + 16777216;              // 131072 (dead after dist)
    float*    pmin     = ws + 16908288;              // 524288
    float*    psec     = ws + 17432576;              // 524288
    int*      pidx     = (int*)(ws + 17956864);      // 524288
    int*      idx_int  = (int*)(ws + 18481152);      // 131072
    int*      rowlist  = (int*)(ws + 18612224);      // 131072
    float*    esq      = ws + 18743296;              // 512
    unsigned* counts   = (unsigned*)(ws + 18743808); // 512
    float*    loss_sum = ws + 18744320;              // 1
    int*      nflag    = (int*)(ws + 18744321);      // 1

    // overlays (hosts dead when used):
    ushort* EWh = (ushort*)(ws + 16908288);          // over pmin (pre-dist)
    ushort* EWl = (ushort*)(ws + 17432576);          // over psec (pre-dist)
    ushort* cbh = (ushort*)(ws + 16777216);          // over xsq (post-dist)
    ushort* cbl = (ushort*)(ws + 16793600);          // over xsq
    ushort* Wh  = (ushort*)(ws + 16908288);          // over pmin (post-merge)
    ushort* Wl  = (ushort*)(ws + 17432576);          // over psec (post-merge)
    ushort* Qh  = (ushort*)ws;                       // over flat (post-loss)
    ushort* Ql  = (ushort*)(ws + 8388608);           // over flat

    float* msg_out = out;                     // 67108864
    float* idx_out = out + 67108864;          // 131072
    float* sc_out  = out + 67108864 + 131072; // 5

    zero_kernel<<<1, 512, 0, stream>>>(counts, loss_sum, nflag);
    sq_pairwise<<<NCODES / 32, 256, 0, stream>>>(cb, esq, NCODES);

    // split enc_w -> bf16 hi/lo (overlay pmin/psec; dead until dist)
    split_hi_lo<<<KC_DIM * D_DIM / 4 / 256, 256, 0, stream>>>(enc_w, EWh, EWl, KC_DIM * D_DIM / 4);

    // encoder on matrix cores (approximate, err ~1e-5)
    enc_mfma<<<1024, 256, 0, stream>>>(h, EWh, EWl, enc_b, flat);

    sq_pairwise<<<NROWS / 32, 256, 0, stream>>>(flat, xsq, NROWS);

    // distances + per-colblock best/second/idx
    dist_gemm<<<dim3(NCODES / 128, NROWS / 128), 256, 0, stream>>>(
        flat, cb, xsq, esq, pmin, psec, pidx);

    merge_flag<<<NROWS / 256, 256, 0, stream>>>(pmin, psec, pidx, idx_int, idx_out,
                                                rowlist, nflag);

    // exact numpy-faithful recompute for near-tie rows
    refine_rows<<<2048, 256, 0, stream>>>(h, enc_w, enc_b, cb, esq, rowlist, nflag,
                                          idx_int, idx_out);

    histogram_kernel<<<NROWS / 256, 256, 0, stream>>>(idx_int, counts);

    gather_loss<<<NELEM / (256 * 8), 256, 0, stream>>>(flat, idx_int, cb, loss_sum);

    // splits for decoder (xsq / pmin / psec dead now)
    split_hi_lo<<<NCODES * C_DIM / 4 / 256, 256, 0, stream>>>(cb, cbh, cbl, NCODES * C_DIM / 4);
    split_hi_lo<<<D_DIM * KC_DIM / 4 / 256, 256, 0, stream>>>(dec_w, Wh, Wl, D_DIM * KC_DIM / 4);

    // flat dead -> gather quantized bf16 rows
    build_q<<<NROWS * 16 / 256, 256, 0, stream>>>(idx_int, cbh, cbl, Qh, Ql);

    dec_gemm_bf16<<<4096, 256, 0, stream>>>(Qh, Ql, Wh, Wl, dec_b, msg_out);

    finalize_scalars<<<1, 512, 0, stream>>>(counts, loss_sum, sc_out);
}

// Round 12
// 1060.404 us; speedup vs baseline: 2.2024x; 1.8798x over previous
//
#include <hip/hip_runtime.h>
#include <hip/hip_bf16.h>

// B=16, T=2048, D=2048, K(msg)=4, C=128, KC=512, CODEBOOK=512
#define M_BT      32768
#define KC_DIM    512
#define D_DIM     2048
#define C_DIM     128
#define NROWS     131072
#define NCODES    512
#define NELEM     16777216   // NROWS*C_DIM
#define GAP_EPS   6.0e-4f
#define FLT_BIG   3.4028235e38f

typedef __bf16 bf16x8 __attribute__((ext_vector_type(8)));
typedef float  f32x4  __attribute__((ext_vector_type(4)));

#define AS3(p) ((__attribute__((address_space(3))) void*)(p))
#define AS1(p) ((const __attribute__((address_space(1))) void*)(p))

static __device__ __forceinline__ ushort f2bf(float x) {
    unsigned u = __float_as_uint(x);
    unsigned r = (u + 0x7fffu + ((u >> 16) & 1u)) >> 16;
    return (ushort)r;
}
static __device__ __forceinline__ float bf2f(ushort u) {
    return __uint_as_float(((unsigned)u) << 16);
}

// ---------------- zero counters ----------------
__global__ __launch_bounds__(512)
void zero_kernel(unsigned* __restrict__ counts, float* __restrict__ loss_sum,
                 int* __restrict__ nflag) {
    counts[threadIdx.x] = 0u;
    if (threadIdx.x == 0) { loss_sum[0] = 0.f; nflag[0] = 0; }
}

// ---------------- numpy-pairwise sum of squares per 128-row ----------------
__global__ __launch_bounds__(256)
void sq_pairwise(const float* __restrict__ src, float* __restrict__ dst, int nrows) {
    int t = threadIdx.x;
    int row = blockIdx.x * 32 + (t >> 3);
    int j = t & 7;
    if (row >= nrows) return;
    const float* p = src + (size_t)row * C_DIM + j;
    float v = p[0];
    float r = __fmul_rn(v, v);
#pragma unroll
    for (int i = 1; i < 16; ++i) {
        float u = p[i * 8];
        r = __fadd_rn(r, __fmul_rn(u, u));
    }
    r = __fadd_rn(r, __shfl_xor(r, 1));
    r = __fadd_rn(r, __shfl_xor(r, 2));
    r = __fadd_rn(r, __shfl_xor(r, 4));
    if (j == 0) dst[row] = r;
}

// ---------------- split fp32 matrix into bf16 hi+lo ----------------
__global__ __launch_bounds__(256)
void split_hi_lo(const float* __restrict__ src, ushort* __restrict__ hi,
                 ushort* __restrict__ lo, int n4) {
    int e = blockIdx.x * 256 + threadIdx.x;
    if (e >= n4) return;
    float4 v = *(const float4*)&src[(size_t)e * 4];
    ushort h0 = f2bf(v.x), h1 = f2bf(v.y), h2 = f2bf(v.z), h3 = f2bf(v.w);
    ushort l0 = f2bf(v.x - bf2f(h0)), l1 = f2bf(v.y - bf2f(h1));
    ushort l2 = f2bf(v.z - bf2f(h2)), l3 = f2bf(v.w - bf2f(h3));
    ushort4 H; H.x = h0; H.y = h1; H.z = h2; H.w = h3;
    ushort4 L; L.x = l0; L.y = l1; L.z = l2; L.w = l3;
    *(ushort4*)&hi[(size_t)e * 4] = H;
    *(ushort4*)&lo[(size_t)e * 4] = L;
}

// ---------------- encoder: split-bf16 MFMA GEMM (approximate) ----------------
__global__ __launch_bounds__(256)
void enc_mfma(const float* __restrict__ h, const ushort* __restrict__ EWh,
              const ushort* __restrict__ EWl, const float* __restrict__ bias,
              float* __restrict__ C)
{
    constexpr int K = D_DIM, N = KC_DIM;
    __shared__ ushort Ah[128 * 32], Al[128 * 32], Bh[128 * 32], Bl[128 * 32];
    const int gid = blockIdx.x;                 // 1024 blocks
    const int f   = (gid & 7) * 128 + (gid >> 3);
    const int bx  = f & 3, by = f >> 2;         // 4 col-blocks, 256 row-blocks
    const int row0 = by * 128, col0 = bx * 128;
    const int tid  = threadIdx.x;
    const int lane = tid & 63, wave = tid >> 6;
    const int wm = wave >> 1, wn = wave & 1;

    f32x4 acc[4][4];
#pragma unroll
    for (int i = 0; i < 4; ++i)
#pragma unroll
        for (int j = 0; j < 4; ++j)
#pragma unroll
            for (int q = 0; q < 4; ++q) acc[i][j][q] = 0.f;

    const int fr = lane & 15, s4 = lane >> 4;
    const int arow = tid >> 3, ak8 = tid & 7;

    for (int kt = 0; kt < K / 32; ++kt) {
        const int k0 = kt * 32;
#pragma unroll
        for (int r = 0; r < 2; ++r) {
            const int t2 = r * 256 + wave * 64 + lane;
            const int ro = t2 >> 2, sb = t2 & 3;
            const int base = (r * 256 + wave * 64) * 8;
            const size_t gb = (size_t)(col0 + ro) * K + k0 + sb * 8;
            __builtin_amdgcn_global_load_lds(AS1(EWh + gb), AS3(&Bh[base]), 16, 0, 0);
            __builtin_amdgcn_global_load_lds(AS1(EWl + gb), AS3(&Bl[base]), 16, 0, 0);
        }
#pragma unroll
        for (int q = 0; q < 4; ++q) {
            const int row = q * 32 + arow;
            float4 v = *(const float4*)&h[(size_t)(row0 + row) * K + k0 + ak8 * 4];
            ushort h0 = f2bf(v.x), h1 = f2bf(v.y), h2 = f2bf(v.z), h3 = f2bf(v.w);
            ushort l0 = f2bf(v.x - bf2f(h0)), l1 = f2bf(v.y - bf2f(h1));
            ushort l2 = f2bf(v.z - bf2f(h2)), l3 = f2bf(v.w - bf2f(h3));
            ushort4 H; H.x = h0; H.y = h1; H.z = h2; H.w = h3;
            ushort4 L; L.x = l0; L.y = l1; L.z = l2; L.w = l3;
            *(ushort4*)&Ah[row * 32 + ak8 * 4] = H;
            *(ushort4*)&Al[row * 32 + ak8 * 4] = L;
        }
        __syncthreads();

        bf16x8 ah[4], al[4], bh[4], bl[4];
#pragma unroll
        for (int mi = 0; mi < 4; ++mi) {
            const int off = (wm * 64 + mi * 16 + fr) * 32 + s4 * 8;
            ah[mi] = *(const bf16x8*)&Ah[off];
            al[mi] = *(const bf16x8*)&Al[off];
        }
#pragma unroll
        for (int ni = 0; ni < 4; ++ni) {
            const int off = (wn * 64 + ni * 16 + fr) * 32 + s4 * 8;
            bh[ni] = *(const bf16x8*)&Bh[off];
            bl[ni] = *(const bf16x8*)&Bl[off];
        }
#pragma unroll
        for (int mi = 0; mi < 4; ++mi)
#pragma unroll
            for (int ni = 0; ni < 4; ++ni) {
                acc[mi][ni] = __builtin_amdgcn_mfma_f32_16x16x32_bf16(ah[mi], bh[ni], acc[mi][ni], 0, 0, 0);
                acc[mi][ni] = __builtin_amdgcn_mfma_f32_16x16x32_bf16(ah[mi], bl[ni], acc[mi][ni], 0, 0, 0);
                acc[mi][ni] = __builtin_amdgcn_mfma_f32_16x16x32_bf16(al[mi], bh[ni], acc[mi][ni], 0, 0, 0);
            }
        __syncthreads();
    }

#pragma unroll
    for (int ni = 0; ni < 4; ++ni) {
        const int c = col0 + wn * 64 + ni * 16 + fr;
        const float bv = bias[c];
#pragma unroll
        for (int mi = 0; mi < 4; ++mi) {
            const int r = row0 + wm * 64 + mi * 16 + s4 * 4;
#pragma unroll
            for (int q = 0; q < 4; ++q)
                C[(size_t)(r + q) * N + c] = acc[mi][ni][q] + bv;
        }
    }
}

// ---------------- dist GEMM: 128x128, 8x8, K=128, best+second epilogue ----------
__global__ __launch_bounds__(256)
void dist_gemm(const float* __restrict__ A, const float* __restrict__ B,
               const float* __restrict__ xsq, const float* __restrict__ esq,
               float* __restrict__ pmin, float* __restrict__ psec,
               int* __restrict__ pidx)
{
    constexpr int K = C_DIM;
    __shared__ __align__(128) float As[4096];
    __shared__ __align__(128) float Bs[4096];
    const int tid  = threadIdx.x;
    const int ty   = tid >> 4, tx = tid & 15;
    const int lane = tid & 63, wave = tid >> 6;
    const int row0 = blockIdx.y * 128, col0 = blockIdx.x * 128;

    float acc[8][8];
#pragma unroll
    for (int i = 0; i < 8; ++i)
#pragma unroll
        for (int j = 0; j < 8; ++j) acc[i][j] = 0.f;

    size_t aoff[4], boff[4];
    int lb[4];
#pragma unroll
    for (int rr = 0; rr < 4; ++rr) {
        const int g = wave * 4 + rr;
        const int r = g * 8 + (lane >> 3);
        const int c = (lane & 7) ^ (g & 7);
        aoff[rr] = (size_t)(row0 + r) * K + c * 4;
        boff[rr] = (size_t)(col0 + r) * K + c * 4;
        lb[rr]   = g * 256;
    }

    const int sa = ty & 7, sb = tx & 7;

    for (int k0 = 0; k0 < K; k0 += 32) {
#pragma unroll
        for (int rr = 0; rr < 4; ++rr) {
            __builtin_amdgcn_global_load_lds(AS1(A + aoff[rr] + k0), AS3(As + lb[rr]), 16, 0, 0);
            __builtin_amdgcn_global_load_lds(AS1(B + boff[rr] + k0), AS3(Bs + lb[rr]), 16, 0, 0);
        }
        __syncthreads();

        const char* Ab = (const char*)&As[ty * 8 * 32] + (sa << 4);
        const char* Bb = (const char*)&Bs[tx * 8 * 32] + (sb << 4);
#pragma unroll
        for (int kk = 0; kk < 8; ++kk) {
            const char* ar = (const char*)((uintptr_t)Ab ^ (unsigned)(kk << 4));
            const char* br = (const char*)((uintptr_t)Bb ^ (unsigned)(kk << 4));
            float4 b4[8];
#pragma unroll
            for (int j = 0; j < 8; ++j)
                b4[j] = *(const float4*)(br + j * 128);
#pragma unroll
            for (int i = 0; i < 8; ++i) {
                float4 a4 = *(const float4*)(ar + i * 128);
#pragma unroll
                for (int j = 0; j < 8; ++j) {
                    float t = acc[i][j];
                    t = fmaf(a4.x, b4[j].x, t);
                    t = fmaf(a4.y, b4[j].y, t);
                    t = fmaf(a4.z, b4[j].z, t);
                    t = fmaf(a4.w, b4[j].w, t);
                    acc[i][j] = t;
                }
            }
        }
        __syncthreads();
    }

    float (*rmin)[16] = (float (*)[16])As;
    float (*rsec)[16] = (float (*)[16])(As + 2048);
    int   (*ridx)[16] = (int   (*)[16])Bs;
    float es[8];
#pragma unroll
    for (int j = 0; j < 8; ++j) es[j] = esq[col0 + tx * 8 + j];
#pragma unroll
    for (int i = 0; i < 8; ++i) {
        float xs = xsq[row0 + ty * 8 + i];
        float b = __fadd_rn(__fsub_rn(xs, __fmul_rn(2.0f, acc[i][0])), es[0]);
        int bi = col0 + tx * 8;
        float sde = FLT_BIG;
#pragma unroll
        for (int j = 1; j < 8; ++j) {
            float d = __fadd_rn(__fsub_rn(xs, __fmul_rn(2.0f, acc[i][j])), es[j]);
            if (d < b) { sde = b; b = d; bi = col0 + tx * 8 + j; }
            else       { sde = fminf(sde, d); }
        }
        rmin[ty * 8 + i][tx] = b;
        rsec[ty * 8 + i][tx] = sde;
        ridx[ty * 8 + i][tx] = bi;
    }
    __syncthreads();
    if (tid < 128) {
        float b = rmin[tid][0], sde = rsec[tid][0]; int ix = ridx[tid][0];
#pragma unroll
        for (int t = 1; t < 16; ++t) {
            float b2 = rmin[tid][t], s2 = rsec[tid][t];
            if (b2 < b) { sde = fminf(b, s2); b = b2; ix = ridx[tid][t]; }
            else        { sde = fminf(sde, b2); }
        }
        size_t o = (size_t)(row0 + tid) * gridDim.x + blockIdx.x;
        pmin[o] = b; psec[o] = sde; pidx[o] = ix;
    }
}

// ---------------- merge 4 col-blocks -> idx + near-tie flags ----------------
__global__ __launch_bounds__(256)
void merge_flag(const float* __restrict__ pmin, const float* __restrict__ psec,
                const int* __restrict__ pidx, int* __restrict__ idx_int,
                float* __restrict__ idx_f, int* __restrict__ rowlist,
                int* __restrict__ nflag) {
    int row = blockIdx.x * 256 + threadIdx.x;
    size_t base = (size_t)row * 4;
    float b = pmin[base], sde = psec[base]; int ix = pidx[base];
#pragma unroll
    for (int nb = 1; nb < 4; ++nb) {
        float b2 = pmin[base + nb], s2 = psec[base + nb];
        if (b2 < b) { sde = fminf(b, s2); b = b2; ix = pidx[base + nb]; }
        else        { sde = fminf(sde, b2); }
    }
    idx_int[row] = ix;
    idx_f[row] = (float)ix;
    if (sde - b < GAP_EPS) {
        int p = atomicAdd(nflag, 1);
        rowlist[p] = row;
    }
}

// ---------------- exact recompute of near-tie rows (numpy-bit-exact) ----------
__global__ __launch_bounds__(256)
void refine_rows(const float* __restrict__ h, const float* __restrict__ enc_w,
                 const float* __restrict__ enc_b, const float* __restrict__ cb,
                 const float* __restrict__ esq, const int* __restrict__ rowlist,
                 const int* __restrict__ nflag_p, int* __restrict__ idx_int,
                 float* __restrict__ idx_f)
{
    __shared__ __align__(16) float x[C_DIM];
    __shared__ float xs_sh;
    __shared__ float rb[256];
    __shared__ int   ri[256];
    const int tid = threadIdx.x;
    const int nf = *nflag_p;
    for (int fi = blockIdx.x; fi < nf; fi += gridDim.x) {
        const int row = rowlist[fi];
        const int bt = row >> 2, seg = row & 3;
        // exact encoder element (sequential k, kc=384 folds). FMA chain order is
        // enforced by data dependence; unroll only batches the loads.
        if (tid < C_DIM) {
            const float* hp = h + (size_t)bt * D_DIM;
            const float* wp = enc_w + (size_t)(seg * C_DIM + tid) * D_DIM;
            float acc = 0.f, accC = 0.f;
            int fold = 96;   // 384/4
#pragma unroll 8
            for (int d = 0; d < D_DIM; d += 4) {
                float4 hv = *(const float4*)(hp + d);
                float4 wv = *(const float4*)(wp + d);
                accC = fmaf(hv.x, wv.x, accC);
                accC = fmaf(hv.y, wv.y, accC);
                accC = fmaf(hv.z, wv.z, accC);
                accC = fmaf(hv.w, wv.w, accC);
                if (--fold == 0) { acc = __fadd_rn(acc, accC); accC = 0.f; fold = 96; }
            }
            acc = __fadd_rn(acc, accC);   // K%384=128 remainder
            x[tid] = __fadd_rn(acc, enc_b[seg * C_DIM + tid]);
        }
        __syncthreads();
        // exact x_sq: numpy pairwise-8 bracket
        if (tid == 0) {
            float rj[8];
#pragma unroll
            for (int j = 0; j < 8; ++j) rj[j] = __fmul_rn(x[j], x[j]);
            for (int i = 1; i < 16; ++i)
#pragma unroll
                for (int j = 0; j < 8; ++j)
                    rj[j] = __fadd_rn(rj[j], __fmul_rn(x[i * 8 + j], x[i * 8 + j]));
            float a01 = __fadd_rn(rj[0], rj[1]);
            float a23 = __fadd_rn(rj[2], rj[3]);
            float a45 = __fadd_rn(rj[4], rj[5]);
            float a67 = __fadd_rn(rj[6], rj[7]);
            xs_sh = __fadd_rn(__fadd_rn(a01, a23), __fadd_rn(a45, a67));
        }
        __syncthreads();
        const float xs = xs_sh;
        // exact dists: thread t -> codes 2t, 2t+1 (sequential fmaf chains)
        float best; int bi;
        {
            const int c0 = tid * 2;
            const float* e0 = cb + (size_t)c0 * C_DIM;
            float dot0 = 0.f, dot1 = 0.f;
#pragma unroll 4
            for (int c = 0; c < C_DIM; c += 4) {
                float4 xv  = *(const float4*)&x[c];
                float4 ev0 = *(const float4*)(e0 + c);
                float4 ev1 = *(const float4*)(e0 + C_DIM + c);
                dot0 = fmaf(xv.x, ev0.x, dot0); dot0 = fmaf(xv.y, ev0.y, dot0);
                dot0 = fmaf(xv.z, ev0.z, dot0); dot0 = fmaf(xv.w, ev0.w, dot0);
                dot1 = fmaf(xv.x, ev1.x, dot1); dot1 = fmaf(xv.y, ev1.y, dot1);
                dot1 = fmaf(xv.z, ev1.z, dot1); dot1 = fmaf(xv.w, ev1.w, dot1);
            }
            float d0 = __fadd_rn(__fsub_rn(xs, __fmul_rn(2.0f, dot0)), esq[c0]);
            float d1 = __fadd_rn(__fsub_rn(xs, __fmul_rn(2.0f, dot1)), esq[c0 + 1]);
            if (d1 < d0) { best = d1; bi = c0 + 1; } else { best = d0; bi = c0; }
        }
        rb[tid] = best; ri[tid] = bi;
        __syncthreads();
        for (int st = 128; st; st >>= 1) {
            if (tid < st) {
                float d2 = rb[tid + st]; int i2 = ri[tid + st];
                if (d2 < rb[tid] || (d2 == rb[tid] && i2 < ri[tid])) {
                    rb[tid] = d2; ri[tid] = i2;
                }
            }
            __syncthreads();
        }
        if (tid == 0) { idx_int[row] = ri[0]; idx_f[row] = (float)ri[0]; }
        __syncthreads();
    }
}

// ---------------- histogram over final indices ----------------
__global__ __launch_bounds__(256)
void histogram_kernel(const int* __restrict__ idx_int, unsigned* __restrict__ counts) {
    __shared__ unsigned hist[NCODES];
    int t = threadIdx.x;
    hist[t] = 0u; hist[t + 256] = 0u;
    __syncthreads();
    int row = blockIdx.x * 256 + t;
    atomicAdd(&hist[idx_int[row]], 1u);
    __syncthreads();
    if (hist[t]) atomicAdd(&counts[t], hist[t]);
    if (hist[t + 256]) atomicAdd(&counts[t + 256], hist[t + 256]);
}

// ---------------- loss only (reads flat, does NOT modify it) ----------------
__global__ __launch_bounds__(256)
void gather_loss(const float* __restrict__ flat, const int* __restrict__ idx,
                 const float* __restrict__ cb, float* __restrict__ loss_sum) {
    size_t e0 = ((size_t)blockIdx.x * 256 + threadIdx.x) * 8;
    int n = (int)(e0 >> 7);
    int c = (int)(e0 & 127);
    int k = idx[n];
    const float4* qp = (const float4*)(cb + (size_t)k * C_DIM + c);
    float4 q0 = qp[0], q1 = qp[1];
    const float4* fp = (const float4*)(flat + e0);
    float4 f0 = fp[0], f1 = fp[1];
    float s = 0.f, d;
    d = q0.x - f0.x; s += d * d;  d = q0.y - f0.y; s += d * d;
    d = q0.z - f0.z; s += d * d;  d = q0.w - f0.w; s += d * d;
    d = q1.x - f1.x; s += d * d;  d = q1.y - f1.y; s += d * d;
    d = q1.z - f1.z; s += d * d;  d = q1.w - f1.w; s += d * d;

    __shared__ float redf[256];
    redf[threadIdx.x] = s;
    __syncthreads();
    for (int st = 128; st; st >>= 1) {
        if (threadIdx.x < st) redf[threadIdx.x] += redf[threadIdx.x + st];
        __syncthreads();
    }
    if (threadIdx.x == 0) atomicAdd(loss_sum, redf[0]);
}

// ---------------- gather split-bf16 quantized rows ----------------
__global__ __launch_bounds__(256)
void build_q(const int* __restrict__ idx, const ushort* __restrict__ cbh,
             const ushort* __restrict__ cbl, ushort* __restrict__ Qh,
             ushort* __restrict__ Ql) {
    int t = blockIdx.x * 256 + threadIdx.x;   // 16B chunk id
    int n = t >> 4, c8 = t & 15;
    int k = idx[n];
    uint4 vh = *(const uint4*)&cbh[(size_t)k * C_DIM + c8 * 8];
    uint4 vl = *(const uint4*)&cbl[(size_t)k * C_DIM + c8 * 8];
    *(uint4*)&Qh[(size_t)n * C_DIM + c8 * 8] = vh;
    *(uint4*)&Ql[(size_t)n * C_DIM + c8 * 8] = vl;
}

// ---------------- decoder: split-bf16 MFMA GEMM, XCD-swizzled 1-D grid ----------------
__global__ __launch_bounds__(256)
void dec_gemm_bf16(const ushort* __restrict__ Qh, const ushort* __restrict__ Ql,
                   const ushort* __restrict__ Wh, const ushort* __restrict__ Wl,
                   const float* __restrict__ bias, float* __restrict__ C)
{
    constexpr int Kd = 512, Nd = 2048;
    __shared__ ushort Ah[128 * 32], Al[128 * 32], Bh[128 * 32], Bl[128 * 32];
    const int gid = blockIdx.x;                       // 4096 blocks
    const int f   = (gid & 7) * 512 + (gid >> 3);
    const int bx  = f & 15, by = f >> 4;
    const int tid  = threadIdx.x;
    const int lane = tid & 63, wave = tid >> 6;
    const int wm = wave >> 1, wn = wave & 1;
    const int row0 = by * 128, col0 = bx * 128;

    f32x4 acc[4][4];
#pragma unroll
    for (int i = 0; i < 4; ++i)
#pragma unroll
        for (int j = 0; j < 4; ++j)
#pragma unroll
            for (int q = 0; q < 4; ++q) acc[i][j][q] = 0.f;

    const int fr = lane & 15, s4 = lane >> 4;

    for (int kt = 0; kt < Kd / 32; ++kt) {
        const int k0 = kt * 32;
#pragma unroll
        for (int r = 0; r < 2; ++r) {
            const int t2 = r * 256 + wave * 64 + lane;
            const int ro = t2 >> 2, sb = t2 & 3;
            const int base = (r * 256 + wave * 64) * 8;
            const size_t ga = (size_t)(row0 + ro) * Kd + k0 + sb * 8;
            const size_t gb = (size_t)(col0 + ro) * Kd + k0 + sb * 8;
            __builtin_amdgcn_global_load_lds(AS1(Qh + ga), AS3(&Ah[base]), 16, 0, 0);
            __builtin_amdgcn_global_load_lds(AS1(Ql + ga), AS3(&Al[base]), 16, 0, 0);
            __builtin_amdgcn_global_load_lds(AS1(Wh + gb), AS3(&Bh[base]), 16, 0, 0);
            __builtin_amdgcn_global_load_lds(AS1(Wl + gb), AS3(&Bl[base]), 16, 0, 0);
        }
        __syncthreads();

        bf16x8 ah[4], al[4], bh[4], bl[4];
#pragma unroll
        for (int mi = 0; mi < 4; ++mi) {
            const int off = (wm * 64 + mi * 16 + fr) * 32 + s4 * 8;
            ah[mi] = *(const bf16x8*)&Ah[off];
            al[mi] = *(const bf16x8*)&Al[off];
        }
#pragma unroll
        for (int ni = 0; ni < 4; ++ni) {
            const int off = (wn * 64 + ni * 16 + fr) * 32 + s4 * 8;
            bh[ni] = *(const bf16x8*)&Bh[off];
            bl[ni] = *(const bf16x8*)&Bl[off];
        }
#pragma unroll
        for (int mi = 0; mi < 4; ++mi)
#pragma unroll
            for (int ni = 0; ni < 4; ++ni) {
                acc[mi][ni] = __builtin_amdgcn_mfma_f32_16x16x32_bf16(ah[mi], bh[ni], acc[mi][ni], 0, 0, 0);
                acc[mi][ni] = __builtin_amdgcn_mfma_f32_16x16x32_bf16(ah[mi], bl[ni], acc[mi][ni], 0, 0, 0);
                acc[mi][ni] = __builtin_amdgcn_mfma_f32_16x16x32_bf16(al[mi], bh[ni], acc[mi][ni], 0, 0, 0);
            }
        __syncthreads();
    }

#pragma unroll
    for (int ni = 0; ni < 4; ++ni) {
        const int c = col0 + wn * 64 + ni * 16 + fr;
        const float bv = bias[c];
#pragma unroll
        for (int mi = 0; mi < 4; ++mi) {
            const int r = row0 + wm * 64 + mi * 16 + s4 * 4;
#pragma unroll
            for (int q = 0; q < 4; ++q)
                C[(size_t)(r + q) * Nd + c] = acc[mi][ni][q] + bv;
        }
    }
}

// ---------------- scalars ----------------
__global__ __launch_bounds__(512)
void finalize_scalars(const unsigned* __restrict__ counts,
                      const float* __restrict__ loss_sum, float* __restrict__ out5) {
    __shared__ float rent[512];
    __shared__ float ruse[512];
    int t = threadIdx.x;
    float c = (float)counts[t];
    float avg = c * (1.0f / (float)NROWS);
    rent[t] = avg * logf(avg + 1e-10f);
    ruse[t] = counts[t] > 0u ? 1.f : 0.f;
    __syncthreads();
    for (int st = 256; st; st >>= 1) {
        if (t < st) { rent[t] += rent[t + st]; ruse[t] += ruse[t + st]; }
        __syncthreads();
    }
    if (t == 0) {
        float H = -rent[0];
        float perp = expf(H);
        float cl = loss_sum[0] * (1.0f / (float)NELEM);
        out5[0] = cl + 0.25f * cl;
        out5[1] = cl;
        out5[2] = cl;
        out5[3] = perp;
        out5[4] = ruse[0] * (1.0f / (float)NCODES);
    }
}

extern "C" void kernel_launch(void* const* d_in, const int* in_sizes, int n_in,
                              void* d_out, int out_size, void* d_ws, size_t ws_size,
                              hipStream_t stream) {
    const float* h     = (const float*)d_in[0];
    const float* enc_w = (const float*)d_in[1];
    const float* enc_b = (const float*)d_in[2];
    const float* cb    = (const float*)d_in[3];
    const float* dec_w = (const float*)d_in[4];
    const float* dec_b = (const float*)d_in[5];
    float* out = (float*)d_out;

    float* ws = (float*)d_ws;
    float*    flat     = ws;                         // [0, 16777216)
    float*    xsq      = ws + 16777216;              // 131072 (dead after dist)
    float*    pmin     = ws + 16908288;              // 524288
    float*    psec     = ws + 17432576;              // 524288
    int*      pidx     = (int*)(ws + 17956864);      // 524288
    int*      idx_int  = (int*)(ws + 18481152);      // 131072
    int*      rowlist  = (int*)(ws + 18612224);      // 131072
    float*    esq      = ws + 18743296;              // 512
    unsigned* counts   = (unsigned*)(ws + 18743808); // 512
    float*    loss_sum = ws + 18744320;              // 1
    int*      nflag    = (int*)(ws + 18744321);      // 1

    // overlays (hosts dead when used):
    ushort* EWh = (ushort*)(ws + 16908288);          // over pmin (pre-dist)
    ushort* EWl = (ushort*)(ws + 17432576);          // over psec (pre-dist)
    ushort* cbh = (ushort*)(ws + 16777216);          // over xsq (post-dist)
    ushort* cbl = (ushort*)(ws + 16793600);          // over xsq
    ushort* Wh  = (ushort*)(ws + 16908288);          // over pmin (post-merge)
    ushort* Wl  = (ushort*)(ws + 17432576);          // over psec (post-merge)
    ushort* Qh  = (ushort*)ws;                       // over flat (post-loss)
    ushort* Ql  = (ushort*)(ws + 8388608);           // over flat

    float* msg_out = out;                     // 67108864
    float* idx_out = out + 67108864;          // 131072
    float* sc_out  = out + 67108864 + 131072; // 5

    zero_kernel<<<1, 512, 0, stream>>>(counts, loss_sum, nflag);
    sq_pairwise<<<NCODES / 32, 256, 0, stream>>>(cb, esq, NCODES);

    // split enc_w -> bf16 hi/lo (overlay pmin/psec; dead until dist)
    split_hi_lo<<<KC_DIM * D_DIM / 4 / 256, 256, 0, stream>>>(enc_w, EWh, EWl, KC_DIM * D_DIM / 4);

    // encoder on matrix cores (approximate, err ~1e-5)
    enc_mfma<<<1024, 256, 0, stream>>>(h, EWh, EWl, enc_b, flat);

    sq_pairwise<<<NROWS / 32, 256, 0, stream>>>(flat, xsq, NROWS);

    // distances + per-colblock best/second/idx
    dist_gemm<<<dim3(NCODES / 128, NROWS / 128), 256, 0, stream>>>(
        flat, cb, xsq, esq, pmin, psec, pidx);

    merge_flag<<<NROWS / 256, 256, 0, stream>>>(pmin, psec, pidx, idx_int, idx_out,
                                                rowlist, nflag);

    // exact numpy-faithful recompute for near-tie rows
    refine_rows<<<2048, 256, 0, stream>>>(h, enc_w, enc_b, cb, esq, rowlist, nflag,
                                          idx_int, idx_out);

    histogram_kernel<<<NROWS / 256, 256, 0, stream>>>(idx_int, counts);

    gather_loss<<<NELEM / (256 * 8), 256, 0, stream>>>(flat, idx_int, cb, loss_sum);

    // splits for decoder (xsq / pmin / psec dead now)
    split_hi_lo<<<NCODES * C_DIM / 4 / 256, 256, 0, stream>>>(cb, cbh, cbl, NCODES * C_DIM / 4);
    split_hi_lo<<<D_DIM * KC_DIM / 4 / 256, 256, 0, stream>>>(dec_w, Wh, Wl, D_DIM * KC_DIM / 4);

    // flat dead -> gather quantized bf16 rows
    build_q<<<NROWS * 16 / 256, 256, 0, stream>>>(idx_int, cbh, cbl, Qh, Ql);

    dec_gemm_bf16<<<4096, 256, 0, stream>>>(Qh, Ql, Wh, Wl, dec_b, msg_out);

    finalize_scalars<<<1, 512, 0, stream>>>(counts, loss_sum, sc_out);
}

// Round 14
// 876.485 us; speedup vs baseline: 2.6645x; 1.2098x over previous
//
#include <hip/hip_runtime.h>
#include <hip/hip_bf16.h>

// B=16, T=2048, D=2048, K(msg)=4, C=128, KC=512, CODEBOOK=512
#define M_BT      32768
#define KC_DIM    512
#define D_DIM     2048
#define C_DIM     128
#define NROWS     131072
#define NCODES    512
#define NELEM     16777216   // NROWS*C_DIM
#define GAP_EPS   6.0e-4f
#define FLT_BIG   3.4028235e38f

typedef __bf16 bf16x8 __attribute__((ext_vector_type(8)));
typedef float  f32x4  __attribute__((ext_vector_type(4)));

#define AS3(p) ((__attribute__((address_space(3))) void*)(p))
#define AS1(p) ((const __attribute__((address_space(1))) void*)(p))

static __device__ __forceinline__ ushort f2bf(float x) {
    unsigned u = __float_as_uint(x);
    unsigned r = (u + 0x7fffu + ((u >> 16) & 1u)) >> 16;
    return (ushort)r;
}
static __device__ __forceinline__ float bf2f(ushort u) {
    return __uint_as_float(((unsigned)u) << 16);
}

// ---------------- zero counters ----------------
__global__ __launch_bounds__(512)
void zero_kernel(unsigned* __restrict__ counts, float* __restrict__ loss_sum,
                 int* __restrict__ nflag) {
    counts[threadIdx.x] = 0u;
    if (threadIdx.x == 0) { loss_sum[0] = 0.f; nflag[0] = 0; }
}

// ---------------- numpy-pairwise sum of squares per 128-row ----------------
__global__ __launch_bounds__(256)
void sq_pairwise(const float* __restrict__ src, float* __restrict__ dst, int nrows) {
    int t = threadIdx.x;
    int row = blockIdx.x * 32 + (t >> 3);
    int j = t & 7;
    if (row >= nrows) return;
    const float* p = src + (size_t)row * C_DIM + j;
    float v = p[0];
    float r = __fmul_rn(v, v);
#pragma unroll
    for (int i = 1; i < 16; ++i) {
        float u = p[i * 8];
        r = __fadd_rn(r, __fmul_rn(u, u));
    }
    r = __fadd_rn(r, __shfl_xor(r, 1));
    r = __fadd_rn(r, __shfl_xor(r, 2));
    r = __fadd_rn(r, __shfl_xor(r, 4));
    if (j == 0) dst[row] = r;
}

// ---------------- split fp32 matrix into bf16 hi+lo ----------------
__global__ __launch_bounds__(256)
void split_hi_lo(const float* __restrict__ src, ushort* __restrict__ hi,
                 ushort* __restrict__ lo, int n4) {
    int e = blockIdx.x * 256 + threadIdx.x;
    if (e >= n4) return;
    float4 v = *(const float4*)&src[(size_t)e * 4];
    ushort h0 = f2bf(v.x), h1 = f2bf(v.y), h2 = f2bf(v.z), h3 = f2bf(v.w);
    ushort l0 = f2bf(v.x - bf2f(h0)), l1 = f2bf(v.y - bf2f(h1));
    ushort l2 = f2bf(v.z - bf2f(h2)), l3 = f2bf(v.w - bf2f(h3));
    ushort4 H; H.x = h0; H.y = h1; H.z = h2; H.w = h3;
    ushort4 L; L.x = l0; L.y = l1; L.z = l2; L.w = l3;
    *(ushort4*)&hi[(size_t)e * 4] = H;
    *(ushort4*)&lo[(size_t)e * 4] = L;
}

// ---------------- encoder: split-bf16 MFMA GEMM (approximate) ----------------
__global__ __launch_bounds__(256)
void enc_mfma(const float* __restrict__ h, const ushort* __restrict__ EWh,
              const ushort* __restrict__ EWl, const float* __restrict__ bias,
              float* __restrict__ C)
{
    constexpr int K = D_DIM, N = KC_DIM;
    __shared__ ushort Ah[128 * 32], Al[128 * 32], Bh[128 * 32], Bl[128 * 32];
    const int gid = blockIdx.x;                 // 1024 blocks
    const int f   = (gid & 7) * 128 + (gid >> 3);
    const int bx  = f & 3, by = f >> 2;         // 4 col-blocks, 256 row-blocks
    const int row0 = by * 128, col0 = bx * 128;
    const int tid  = threadIdx.x;
    const int lane = tid & 63, wave = tid >> 6;
    const int wm = wave >> 1, wn = wave & 1;

    f32x4 acc[4][4];
#pragma unroll
    for (int i = 0; i < 4; ++i)
#pragma unroll
        for (int j = 0; j < 4; ++j)
#pragma unroll
            for (int q = 0; q < 4; ++q) acc[i][j][q] = 0.f;

    const int fr = lane & 15, s4 = lane >> 4;
    const int arow = tid >> 3, ak8 = tid & 7;

    for (int kt = 0; kt < K / 32; ++kt) {
        const int k0 = kt * 32;
#pragma unroll
        for (int r = 0; r < 2; ++r) {
            const int t2 = r * 256 + wave * 64 + lane;
            const int ro = t2 >> 2, sb = t2 & 3;
            const int base = (r * 256 + wave * 64) * 8;
            const size_t gb = (size_t)(col0 + ro) * K + k0 + sb * 8;
            __builtin_amdgcn_global_load_lds(AS1(EWh + gb), AS3(&Bh[base]), 16, 0, 0);
            __builtin_amdgcn_global_load_lds(AS1(EWl + gb), AS3(&Bl[base]), 16, 0, 0);
        }
#pragma unroll
        for (int q = 0; q < 4; ++q) {
            const int row = q * 32 + arow;
            float4 v = *(const float4*)&h[(size_t)(row0 + row) * K + k0 + ak8 * 4];
            ushort h0 = f2bf(v.x), h1 = f2bf(v.y), h2 = f2bf(v.z), h3 = f2bf(v.w);
            ushort l0 = f2bf(v.x - bf2f(h0)), l1 = f2bf(v.y - bf2f(h1));
            ushort l2 = f2bf(v.z - bf2f(h2)), l3 = f2bf(v.w - bf2f(h3));
            ushort4 H; H.x = h0; H.y = h1; H.z = h2; H.w = h3;
            ushort4 L; L.x = l0; L.y = l1; L.z = l2; L.w = l3;
            *(ushort4*)&Ah[row * 32 + ak8 * 4] = H;
            *(ushort4*)&Al[row * 32 + ak8 * 4] = L;
        }
        __syncthreads();

        bf16x8 ah[4], al[4], bh[4], bl[4];
#pragma unroll
        for (int mi = 0; mi < 4; ++mi) {
            const int off = (wm * 64 + mi * 16 + fr) * 32 + s4 * 8;
            ah[mi] = *(const bf16x8*)&Ah[off];
            al[mi] = *(const bf16x8*)&Al[off];
        }
#pragma unroll
        for (int ni = 0; ni < 4; ++ni) {
            const int off = (wn * 64 + ni * 16 + fr) * 32 + s4 * 8;
            bh[ni] = *(const bf16x8*)&Bh[off];
            bl[ni] = *(const bf16x8*)&Bl[off];
        }
#pragma unroll
        for (int mi = 0; mi < 4; ++mi)
#pragma unroll
            for (int ni = 0; ni < 4; ++ni) {
                acc[mi][ni] = __builtin_amdgcn_mfma_f32_16x16x32_bf16(ah[mi], bh[ni], acc[mi][ni], 0, 0, 0);
                acc[mi][ni] = __builtin_amdgcn_mfma_f32_16x16x32_bf16(ah[mi], bl[ni], acc[mi][ni], 0, 0, 0);
                acc[mi][ni] = __builtin_amdgcn_mfma_f32_16x16x32_bf16(al[mi], bh[ni], acc[mi][ni], 0, 0, 0);
            }
        __syncthreads();
    }

#pragma unroll
    for (int ni = 0; ni < 4; ++ni) {
        const int c = col0 + wn * 64 + ni * 16 + fr;
        const float bv = bias[c];
#pragma unroll
        for (int mi = 0; mi < 4; ++mi) {
            const int r = row0 + wm * 64 + mi * 16 + s4 * 4;
#pragma unroll
            for (int q = 0; q < 4; ++q)
                C[(size_t)(r + q) * N + c] = acc[mi][ni][q] + bv;
        }
    }
}

// ---------------- dist on matrix cores: split-bf16 MFMA + argmin epilogue ----------
__global__ __launch_bounds__(256)
void dist_mfma(const float* __restrict__ flat, const ushort* __restrict__ cbh,
               const ushort* __restrict__ cbl, const float* __restrict__ xsq,
               const float* __restrict__ esq, float* __restrict__ pmin,
               float* __restrict__ psec, int* __restrict__ pidx)
{
    constexpr int K = C_DIM;                    // 128
    __shared__ ushort Ah[128 * 32], Al[128 * 32], Bh[128 * 32], Bl[128 * 32];
    const int gid = blockIdx.x;                 // 4096 blocks
    const int f   = (gid & 7) * 512 + (gid >> 3);
    const int bx  = f & 3, by = f >> 2;         // 4 col-blocks, 1024 row-blocks
    const int row0 = by * 128, col0 = bx * 128;
    const int tid  = threadIdx.x;
    const int lane = tid & 63, wave = tid >> 6;
    const int wm = wave >> 1, wn = wave & 1;

    f32x4 acc[4][4];
#pragma unroll
    for (int i = 0; i < 4; ++i)
#pragma unroll
        for (int j = 0; j < 4; ++j)
#pragma unroll
            for (int q = 0; q < 4; ++q) acc[i][j][q] = 0.f;

    const int fr = lane & 15, s4 = lane >> 4;
    const int arow = tid >> 3, ak8 = tid & 7;

    for (int kt = 0; kt < K / 32; ++kt) {
        const int k0 = kt * 32;
#pragma unroll
        for (int r = 0; r < 2; ++r) {
            const int t2 = r * 256 + wave * 64 + lane;
            const int ro = t2 >> 2, sb = t2 & 3;
            const int base = (r * 256 + wave * 64) * 8;
            const size_t gb = (size_t)(col0 + ro) * K + k0 + sb * 8;
            __builtin_amdgcn_global_load_lds(AS1(cbh + gb), AS3(&Bh[base]), 16, 0, 0);
            __builtin_amdgcn_global_load_lds(AS1(cbl + gb), AS3(&Bl[base]), 16, 0, 0);
        }
#pragma unroll
        for (int q = 0; q < 4; ++q) {
            const int row = q * 32 + arow;
            float4 v = *(const float4*)&flat[(size_t)(row0 + row) * K + k0 + ak8 * 4];
            ushort h0 = f2bf(v.x), h1 = f2bf(v.y), h2 = f2bf(v.z), h3 = f2bf(v.w);
            ushort l0 = f2bf(v.x - bf2f(h0)), l1 = f2bf(v.y - bf2f(h1));
            ushort l2 = f2bf(v.z - bf2f(h2)), l3 = f2bf(v.w - bf2f(h3));
            ushort4 H; H.x = h0; H.y = h1; H.z = h2; H.w = h3;
            ushort4 L; L.x = l0; L.y = l1; L.z = l2; L.w = l3;
            *(ushort4*)&Ah[row * 32 + ak8 * 4] = H;
            *(ushort4*)&Al[row * 32 + ak8 * 4] = L;
        }
        __syncthreads();

        bf16x8 ah[4], al[4], bh[4], bl[4];
#pragma unroll
        for (int mi = 0; mi < 4; ++mi) {
            const int off = (wm * 64 + mi * 16 + fr) * 32 + s4 * 8;
            ah[mi] = *(const bf16x8*)&Ah[off];
            al[mi] = *(const bf16x8*)&Al[off];
        }
#pragma unroll
        for (int ni = 0; ni < 4; ++ni) {
            const int off = (wn * 64 + ni * 16 + fr) * 32 + s4 * 8;
            bh[ni] = *(const bf16x8*)&Bh[off];
            bl[ni] = *(const bf16x8*)&Bl[off];
        }
#pragma unroll
        for (int mi = 0; mi < 4; ++mi)
#pragma unroll
            for (int ni = 0; ni < 4; ++ni) {
                acc[mi][ni] = __builtin_amdgcn_mfma_f32_16x16x32_bf16(ah[mi], bh[ni], acc[mi][ni], 0, 0, 0);
                acc[mi][ni] = __builtin_amdgcn_mfma_f32_16x16x32_bf16(ah[mi], bl[ni], acc[mi][ni], 0, 0, 0);
                acc[mi][ni] = __builtin_amdgcn_mfma_f32_16x16x32_bf16(al[mi], bh[ni], acc[mi][ni], 0, 0, 0);
            }
        __syncthreads();
    }

    // epilogue: dist + per-row (best, second, idx). LDS scratch aliases Ah/Al
    float* bB = (float*)Ah;          // [128][2]
    float* sB = (float*)Ah + 256;    // [128][2]
    int*   iB = (int*)Al;            // [128][2]

    float es_v[4];
#pragma unroll
    for (int ni = 0; ni < 4; ++ni) es_v[ni] = esq[col0 + wn * 64 + ni * 16 + fr];

#pragma unroll
    for (int mi = 0; mi < 4; ++mi) {
#pragma unroll
        for (int q = 0; q < 4; ++q) {
            const int r = wm * 64 + mi * 16 + s4 * 4 + q;
            const float xs = xsq[row0 + r];
            float b = FLT_BIG, s = FLT_BIG; int bi = 0;
#pragma unroll
            for (int ni = 0; ni < 4; ++ni) {
                float d = (xs - 2.0f * acc[mi][ni][q]) + es_v[ni];
                int c = col0 + wn * 64 + ni * 16 + fr;
                if (d < b) { s = b; b = d; bi = c; }
                else       { s = fminf(s, d); }
            }
#pragma unroll
            for (int m = 1; m < 16; m <<= 1) {
                float b2 = __shfl_xor(b, m);
                float s2 = __shfl_xor(s, m);
                int   i2 = __shfl_xor(bi, m);
                if (b2 < b || (b2 == b && i2 < bi)) { s = fminf(b, s2); b = b2; bi = i2; }
                else                                { s = fminf(s, b2); }
            }
            if (fr == 0) { bB[r * 2 + wn] = b; sB[r * 2 + wn] = s; iB[r * 2 + wn] = bi; }
        }
    }
    __syncthreads();
    if (tid < 128) {
        float b0 = bB[tid * 2],     s0 = sB[tid * 2];     int i0 = iB[tid * 2];
        float b1 = bB[tid * 2 + 1], s1 = sB[tid * 2 + 1]; int i1 = iB[tid * 2 + 1];
        float b, s; int ix;
        if (b1 < b0) { b = b1; s = fminf(b0, s1); ix = i1; }
        else         { b = b0; s = fminf(s0, b1); ix = i0; }
        size_t o = (size_t)(row0 + tid) * 4 + bx;
        pmin[o] = b; psec[o] = s; pidx[o] = ix;
    }
}

// ---------------- merge 4 col-blocks -> idx + near-tie flags ----------------
__global__ __launch_bounds__(256)
void merge_flag(const float* __restrict__ pmin, const float* __restrict__ psec,
                const int* __restrict__ pidx, int* __restrict__ idx_int,
                float* __restrict__ idx_f, int* __restrict__ rowlist,
                int* __restrict__ nflag) {
    int row = blockIdx.x * 256 + threadIdx.x;
    size_t base = (size_t)row * 4;
    float b = pmin[base], sde = psec[base]; int ix = pidx[base];
#pragma unroll
    for (int nb = 1; nb < 4; ++nb) {
        float b2 = pmin[base + nb], s2 = psec[base + nb];
        if (b2 < b) { sde = fminf(b, s2); b = b2; ix = pidx[base + nb]; }
        else        { sde = fminf(sde, b2); }
    }
    idx_int[row] = ix;
    idx_f[row] = (float)ix;
    if (sde - b < GAP_EPS) {
        int p = atomicAdd(nflag, 1);
        rowlist[p] = row;
    }
}

// ---------------- exact recompute of near-tie rows (numpy-bit-exact) ----------
__global__ __launch_bounds__(256)
void refine_rows(const float* __restrict__ h, const float* __restrict__ enc_w,
                 const float* __restrict__ enc_b, const float* __restrict__ cb,
                 const float* __restrict__ esq, const int* __restrict__ rowlist,
                 const int* __restrict__ nflag_p, int* __restrict__ idx_int,
                 float* __restrict__ idx_f)
{
    __shared__ __align__(16) float x[C_DIM];
    __shared__ float xs_sh;
    __shared__ float rb[256];
    __shared__ int   ri[256];
    const int tid = threadIdx.x;
    const int nf = *nflag_p;
    for (int fi = blockIdx.x; fi < nf; fi += gridDim.x) {
        const int row = rowlist[fi];
        const int bt = row >> 2, seg = row & 3;
        if (tid < C_DIM) {
            const float* hp = h + (size_t)bt * D_DIM;
            const float* wp = enc_w + (size_t)(seg * C_DIM + tid) * D_DIM;
            float acc = 0.f, accC = 0.f;
            int fold = 96;   // 384/4
#pragma unroll 8
            for (int d = 0; d < D_DIM; d += 4) {
                float4 hv = *(const float4*)(hp + d);
                float4 wv = *(const float4*)(wp + d);
                accC = fmaf(hv.x, wv.x, accC);
                accC = fmaf(hv.y, wv.y, accC);
                accC = fmaf(hv.z, wv.z, accC);
                accC = fmaf(hv.w, wv.w, accC);
                if (--fold == 0) { acc = __fadd_rn(acc, accC); accC = 0.f; fold = 96; }
            }
            acc = __fadd_rn(acc, accC);   // K%384=128 remainder
            x[tid] = __fadd_rn(acc, enc_b[seg * C_DIM + tid]);
        }
        __syncthreads();
        if (tid == 0) {
            float rj[8];
#pragma unroll
            for (int j = 0; j < 8; ++j) rj[j] = __fmul_rn(x[j], x[j]);
            for (int i = 1; i < 16; ++i)
#pragma unroll
                for (int j = 0; j < 8; ++j)
                    rj[j] = __fadd_rn(rj[j], __fmul_rn(x[i * 8 + j], x[i * 8 + j]));
            float a01 = __fadd_rn(rj[0], rj[1]);
            float a23 = __fadd_rn(rj[2], rj[3]);
            float a45 = __fadd_rn(rj[4], rj[5]);
            float a67 = __fadd_rn(rj[6], rj[7]);
            xs_sh = __fadd_rn(__fadd_rn(a01, a23), __fadd_rn(a45, a67));
        }
        __syncthreads();
        const float xs = xs_sh;
        float best; int bi;
        {
            const int c0 = tid * 2;
            const float* e0 = cb + (size_t)c0 * C_DIM;
            float dot0 = 0.f, dot1 = 0.f;
#pragma unroll 4
            for (int c = 0; c < C_DIM; c += 4) {
                float4 xv  = *(const float4*)&x[c];
                float4 ev0 = *(const float4*)(e0 + c);
                float4 ev1 = *(const float4*)(e0 + C_DIM + c);
                dot0 = fmaf(xv.x, ev0.x, dot0); dot0 = fmaf(xv.y, ev0.y, dot0);
                dot0 = fmaf(xv.z, ev0.z, dot0); dot0 = fmaf(xv.w, ev0.w, dot0);
                dot1 = fmaf(xv.x, ev1.x, dot1); dot1 = fmaf(xv.y, ev1.y, dot1);
                dot1 = fmaf(xv.z, ev1.z, dot1); dot1 = fmaf(xv.w, ev1.w, dot1);
            }
            float d0 = __fadd_rn(__fsub_rn(xs, __fmul_rn(2.0f, dot0)), esq[c0]);
            float d1 = __fadd_rn(__fsub_rn(xs, __fmul_rn(2.0f, dot1)), esq[c0 + 1]);
            if (d1 < d0) { best = d1; bi = c0 + 1; } else { best = d0; bi = c0; }
        }
        rb[tid] = best; ri[tid] = bi;
        __syncthreads();
        for (int st = 128; st; st >>= 1) {
            if (tid < st) {
                float d2 = rb[tid + st]; int i2 = ri[tid + st];
                if (d2 < rb[tid] || (d2 == rb[tid] && i2 < ri[tid])) {
                    rb[tid] = d2; ri[tid] = i2;
                }
            }
            __syncthreads();
        }
        if (tid == 0) { idx_int[row] = ri[0]; idx_f[row] = (float)ri[0]; }
        __syncthreads();
    }
}

// ---------------- histogram over final indices ----------------
__global__ __launch_bounds__(256)
void histogram_kernel(const int* __restrict__ idx_int, unsigned* __restrict__ counts) {
    __shared__ unsigned hist[NCODES];
    int t = threadIdx.x;
    hist[t] = 0u; hist[t + 256] = 0u;
    __syncthreads();
    int row = blockIdx.x * 256 + t;
    atomicAdd(&hist[idx_int[row]], 1u);
    __syncthreads();
    if (hist[t]) atomicAdd(&counts[t], hist[t]);
    if (hist[t + 256]) atomicAdd(&counts[t + 256], hist[t + 256]);
}

// ---------------- loss only (reads flat, does NOT modify it) ----------------
__global__ __launch_bounds__(256)
void gather_loss(const float* __restrict__ flat, const int* __restrict__ idx,
                 const float* __restrict__ cb, float* __restrict__ loss_sum) {
    size_t e0 = ((size_t)blockIdx.x * 256 + threadIdx.x) * 8;
    int n = (int)(e0 >> 7);
    int c = (int)(e0 & 127);
    int k = idx[n];
    const float4* qp = (const float4*)(cb + (size_t)k * C_DIM + c);
    float4 q0 = qp[0], q1 = qp[1];
    const float4* fp = (const float4*)(flat + e0);
    float4 f0 = fp[0], f1 = fp[1];
    float s = 0.f, d;
    d = q0.x - f0.x; s += d * d;  d = q0.y - f0.y; s += d * d;
    d = q0.z - f0.z; s += d * d;  d = q0.w - f0.w; s += d * d;
    d = q1.x - f1.x; s += d * d;  d = q1.y - f1.y; s += d * d;
    d = q1.z - f1.z; s += d * d;  d = q1.w - f1.w; s += d * d;

    __shared__ float redf[256];
    redf[threadIdx.x] = s;
    __syncthreads();
    for (int st = 128; st; st >>= 1) {
        if (threadIdx.x < st) redf[threadIdx.x] += redf[threadIdx.x + st];
        __syncthreads();
    }
    if (threadIdx.x == 0) atomicAdd(loss_sum, redf[0]);
}

// ---------------- gather split-bf16 quantized rows ----------------
__global__ __launch_bounds__(256)
void build_q(const int* __restrict__ idx, const ushort* __restrict__ cbh,
             const ushort* __restrict__ cbl, ushort* __restrict__ Qh,
             ushort* __restrict__ Ql) {
    int t = blockIdx.x * 256 + threadIdx.x;   // 16B chunk id
    int n = t >> 4, c8 = t & 15;
    int k = idx[n];
    uint4 vh = *(const uint4*)&cbh[(size_t)k * C_DIM + c8 * 8];
    uint4 vl = *(const uint4*)&cbl[(size_t)k * C_DIM + c8 * 8];
    *(uint4*)&Qh[(size_t)n * C_DIM + c8 * 8] = vh;
    *(uint4*)&Ql[(size_t)n * C_DIM + c8 * 8] = vl;
}

// ---------------- decoder: split-bf16 MFMA GEMM, XCD-swizzled 1-D grid ----------------
__global__ __launch_bounds__(256)
void dec_gemm_bf16(const ushort* __restrict__ Qh, const ushort* __restrict__ Ql,
                   const ushort* __restrict__ Wh, const ushort* __restrict__ Wl,
                   const float* __restrict__ bias, float* __restrict__ C)
{
    constexpr int Kd = 512, Nd = 2048;
    __shared__ ushort Ah[128 * 32], Al[128 * 32], Bh[128 * 32], Bl[128 * 32];
    const int gid = blockIdx.x;                       // 4096 blocks
    const int f   = (gid & 7) * 512 + (gid >> 3);
    const int bx  = f & 15, by = f >> 4;
    const int tid  = threadIdx.x;
    const int lane = tid & 63, wave = tid >> 6;
    const int wm = wave >> 1, wn = wave & 1;
    const int row0 = by * 128, col0 = bx * 128;

    f32x4 acc[4][4];
#pragma unroll
    for (int i = 0; i < 4; ++i)
#pragma unroll
        for (int j = 0; j < 4; ++j)
#pragma unroll
            for (int q = 0; q < 4; ++q) acc[i][j][q] = 0.f;

    const int fr = lane & 15, s4 = lane >> 4;

    for (int kt = 0; kt < Kd / 32; ++kt) {
        const int k0 = kt * 32;
#pragma unroll
        for (int r = 0; r < 2; ++r) {
            const int t2 = r * 256 + wave * 64 + lane;
            const int ro = t2 >> 2, sb = t2 & 3;
            const int base = (r * 256 + wave * 64) * 8;
            const size_t ga = (size_t)(row0 + ro) * Kd + k0 + sb * 8;
            const size_t gb = (size_t)(col0 + ro) * Kd + k0 + sb * 8;
            __builtin_amdgcn_global_load_lds(AS1(Qh + ga), AS3(&Ah[base]), 16, 0, 0);
            __builtin_amdgcn_global_load_lds(AS1(Ql + ga), AS3(&Al[base]), 16, 0, 0);
            __builtin_amdgcn_global_load_lds(AS1(Wh + gb), AS3(&Bh[base]), 16, 0, 0);
            __builtin_amdgcn_global_load_lds(AS1(Wl + gb), AS3(&Bl[base]), 16, 0, 0);
        }
        __syncthreads();

        bf16x8 ah[4], al[4], bh[4], bl[4];
#pragma unroll
        for (int mi = 0; mi < 4; ++mi) {
            const int off = (wm * 64 + mi * 16 + fr) * 32 + s4 * 8;
            ah[mi] = *(const bf16x8*)&Ah[off];
            al[mi] = *(const bf16x8*)&Al[off];
        }
#pragma unroll
        for (int ni = 0; ni < 4; ++ni) {
            const int off = (wn * 64 + ni * 16 + fr) * 32 + s4 * 8;
            bh[ni] = *(const bf16x8*)&Bh[off];
            bl[ni] = *(const bf16x8*)&Bl[off];
        }
#pragma unroll
        for (int mi = 0; mi < 4; ++mi)
#pragma unroll
            for (int ni = 0; ni < 4; ++ni) {
                acc[mi][ni] = __builtin_amdgcn_mfma_f32_16x16x32_bf16(ah[mi], bh[ni], acc[mi][ni], 0, 0, 0);
                acc[mi][ni] = __builtin_amdgcn_mfma_f32_16x16x32_bf16(ah[mi], bl[ni], acc[mi][ni], 0, 0, 0);
                acc[mi][ni] = __builtin_amdgcn_mfma_f32_16x16x32_bf16(al[mi], bh[ni], acc[mi][ni], 0, 0, 0);
            }
        __syncthreads();
    }

#pragma unroll
    for (int ni = 0; ni < 4; ++ni) {
        const int c = col0 + wn * 64 + ni * 16 + fr;
        const float bv = bias[c];
#pragma unroll
        for (int mi = 0; mi < 4; ++mi) {
            const int r = row0 + wm * 64 + mi * 16 + s4 * 4;
#pragma unroll
            for (int q = 0; q < 4; ++q)
                C[(size_t)(r + q) * Nd + c] = acc[mi][ni][q] + bv;
        }
    }
}

// ---------------- scalars ----------------
__global__ __launch_bounds__(512)
void finalize_scalars(const unsigned* __restrict__ counts,
                      const float* __restrict__ loss_sum, float* __restrict__ out5) {
    __shared__ float rent[512];
    __shared__ float ruse[512];
    int t = threadIdx.x;
    float c = (float)counts[t];
    float avg = c * (1.0f / (float)NROWS);
    rent[t] = avg * logf(avg + 1e-10f);
    ruse[t] = counts[t] > 0u ? 1.f : 0.f;
    __syncthreads();
    for (int st = 256; st; st >>= 1) {
        if (t < st) { rent[t] += rent[t + st]; ruse[t] += ruse[t + st]; }
        __syncthreads();
    }
    if (t == 0) {
        float H = -rent[0];
        float perp = expf(H);
        float cl = loss_sum[0] * (1.0f / (float)NELEM);
        out5[0] = cl + 0.25f * cl;
        out5[1] = cl;
        out5[2] = cl;
        out5[3] = perp;
        out5[4] = ruse[0] * (1.0f / (float)NCODES);
    }
}

extern "C" void kernel_launch(void* const* d_in, const int* in_sizes, int n_in,
                              void* d_out, int out_size, void* d_ws, size_t ws_size,
                              hipStream_t stream) {
    const float* h     = (const float*)d_in[0];
    const float* enc_w = (const float*)d_in[1];
    const float* enc_b = (const float*)d_in[2];
    const float* cb    = (const float*)d_in[3];
    const float* dec_w = (const float*)d_in[4];
    const float* dec_b = (const float*)d_in[5];
    float* out = (float*)d_out;

    float* ws = (float*)d_ws;
    float*    flat     = ws;                         // [0, 16777216)
    float*    xsq      = ws + 16777216;              // 131072
    float*    pmin     = ws + 16908288;              // 524288
    float*    psec     = ws + 17432576;              // 524288
    int*      pidx     = (int*)(ws + 17956864);      // 524288
    int*      idx_int  = (int*)(ws + 18481152);      // 131072
    int*      rowlist  = (int*)(ws + 18612224);      // 131072
    float*    esq      = ws + 18743296;              // 512
    unsigned* counts   = (unsigned*)(ws + 18743808); // 512
    float*    loss_sum = ws + 18744320;              // 1
    int*      nflag    = (int*)(ws + 18744321);      // 1

    // overlays (hosts dead when used). cb split planes each need 512*128
    // ushorts = 32768 FLOAT-slots -> lo plane must sit +32768 after hi.
    ushort* EWh  = (ushort*)(ws + 16908288);         // over pmin  (pre-dist), 524288 slots
    ushort* EWl  = (ushort*)(ws + 17432576);         // over psec  (pre-dist), 524288 slots
    ushort* cbhd = (ushort*)(ws + 18612224);         // over rowlist[0..32767]   (pre-merge)
    ushort* cbld = (ushort*)(ws + 18644992);         // over rowlist[32768..65535]
    ushort* cbh  = (ushort*)(ws + 16777216);         // over xsq[0..32767]       (post-dist)
    ushort* cbl  = (ushort*)(ws + 16809984);         // over xsq[32768..65535]
    ushort* Wh   = (ushort*)(ws + 16908288);         // over pmin (post-merge)
    ushort* Wl   = (ushort*)(ws + 17432576);         // over psec (post-merge)
    ushort* Qh   = (ushort*)ws;                      // over flat (post-loss)
    ushort* Ql   = (ushort*)(ws + 8388608);          // over flat

    float* msg_out = out;                     // 67108864
    float* idx_out = out + 67108864;          // 131072
    float* sc_out  = out + 67108864 + 131072; // 5

    zero_kernel<<<1, 512, 0, stream>>>(counts, loss_sum, nflag);
    sq_pairwise<<<NCODES / 32, 256, 0, stream>>>(cb, esq, NCODES);

    // split enc_w -> bf16 hi/lo (overlay pmin/psec; dead until dist)
    split_hi_lo<<<KC_DIM * D_DIM / 4 / 256, 256, 0, stream>>>(enc_w, EWh, EWl, KC_DIM * D_DIM / 4);
    // split cb -> bf16 hi/lo for dist (overlay rowlist; dead until merge)
    split_hi_lo<<<NCODES * C_DIM / 4 / 256, 256, 0, stream>>>(cb, cbhd, cbld, NCODES * C_DIM / 4);

    // encoder on matrix cores (approximate, err ~1e-5)
    enc_mfma<<<1024, 256, 0, stream>>>(h, EWh, EWl, enc_b, flat);

    sq_pairwise<<<NROWS / 32, 256, 0, stream>>>(flat, xsq, NROWS);

    // distances on matrix cores + per-colblock best/second/idx
    dist_mfma<<<4096, 256, 0, stream>>>(flat, cbhd, cbld, xsq, esq, pmin, psec, pidx);

    merge_flag<<<NROWS / 256, 256, 0, stream>>>(pmin, psec, pidx, idx_int, idx_out,
                                                rowlist, nflag);

    // exact numpy-faithful recompute for near-tie rows
    refine_rows<<<2048, 256, 0, stream>>>(h, enc_w, enc_b, cb, esq, rowlist, nflag,
                                          idx_int, idx_out);

    histogram_kernel<<<NROWS / 256, 256, 0, stream>>>(idx_int, counts);

    gather_loss<<<NELEM / (256 * 8), 256, 0, stream>>>(flat, idx_int, cb, loss_sum);

    // splits for decoder (xsq / pmin / psec dead now)
    split_hi_lo<<<NCODES * C_DIM / 4 / 256, 256, 0, stream>>>(cb, cbh, cbl, NCODES * C_DIM / 4);
    split_hi_lo<<<D_DIM * KC_DIM / 4 / 256, 256, 0, stream>>>(dec_w, Wh, Wl, D_DIM * KC_DIM / 4);

    // flat dead -> gather quantized bf16 rows
    build_q<<<NROWS * 16 / 256, 256, 0, stream>>>(idx_int, cbh, cbl, Qh, Ql);

    dec_gemm_bf16<<<4096, 256, 0, stream>>>(Qh, Ql, Wh, Wl, dec_b, msg_out);

    finalize_scalars<<<1, 512, 0, stream>>>(counts, loss_sum, sc_out);
}

// Round 15
// 848.848 us; speedup vs baseline: 2.7512x; 1.0326x over previous
//
#include <hip/hip_runtime.h>
#include <hip/hip_bf16.h>

// B=16, T=2048, D=2048, K(msg)=4, C=128, KC=512, CODEBOOK=512
#define M_BT      32768
#define KC_DIM    512
#define D_DIM     2048
#define C_DIM     128
#define NROWS     131072
#define NCODES    512
#define NELEM     16777216   // NROWS*C_DIM
#define GAP_EPS   6.0e-4f
#define FLT_BIG   3.4028235e38f

typedef __bf16 bf16x8 __attribute__((ext_vector_type(8)));
typedef float  f32x4  __attribute__((ext_vector_type(4)));

#define AS3(p) ((__attribute__((address_space(3))) void*)(p))
#define AS1(p) ((const __attribute__((address_space(1))) void*)(p))

static __device__ __forceinline__ ushort f2bf(float x) {
    unsigned u = __float_as_uint(x);
    unsigned r = (u + 0x7fffu + ((u >> 16) & 1u)) >> 16;
    return (ushort)r;
}
static __device__ __forceinline__ float bf2f(ushort u) {
    return __uint_as_float(((unsigned)u) << 16);
}

// ---------------- zero counters ----------------
__global__ __launch_bounds__(512)
void zero_kernel(unsigned* __restrict__ counts, float* __restrict__ loss_sum,
                 int* __restrict__ nflag) {
    counts[threadIdx.x] = 0u;
    if (threadIdx.x == 0) { loss_sum[0] = 0.f; nflag[0] = 0; }
}

// ---------------- numpy-pairwise sum of squares (fp32 input, for e_sq) --------
__global__ __launch_bounds__(256)
void sq_pairwise(const float* __restrict__ src, float* __restrict__ dst, int nrows) {
    int t = threadIdx.x;
    int row = blockIdx.x * 32 + (t >> 3);
    int j = t & 7;
    if (row >= nrows) return;
    const float* p = src + (size_t)row * C_DIM + j;
    float v = p[0];
    float r = __fmul_rn(v, v);
#pragma unroll
    for (int i = 1; i < 16; ++i) {
        float u = p[i * 8];
        r = __fadd_rn(r, __fmul_rn(u, u));
    }
    r = __fadd_rn(r, __shfl_xor(r, 1));
    r = __fadd_rn(r, __shfl_xor(r, 2));
    r = __fadd_rn(r, __shfl_xor(r, 4));
    if (j == 0) dst[row] = r;
}

// ---------------- same, from split-bf16 planes (for x_sq of flat) ----------
__global__ __launch_bounds__(256)
void sq_pairwise_bf(const ushort* __restrict__ Fh, const ushort* __restrict__ Fl,
                    float* __restrict__ dst, int nrows) {
    int t = threadIdx.x;
    int row = blockIdx.x * 32 + (t >> 3);
    int j = t & 7;
    if (row >= nrows) return;
    const ushort* ph = Fh + (size_t)row * C_DIM + j;
    const ushort* pl = Fl + (size_t)row * C_DIM + j;
    float v = bf2f(ph[0]) + bf2f(pl[0]);
    float r = __fmul_rn(v, v);
#pragma unroll
    for (int i = 1; i < 16; ++i) {
        float u = bf2f(ph[i * 8]) + bf2f(pl[i * 8]);
        r = __fadd_rn(r, __fmul_rn(u, u));
    }
    r = __fadd_rn(r, __shfl_xor(r, 1));
    r = __fadd_rn(r, __shfl_xor(r, 2));
    r = __fadd_rn(r, __shfl_xor(r, 4));
    if (j == 0) dst[row] = r;
}

// ---------------- split fp32 matrix into bf16 hi+lo ----------------
__global__ __launch_bounds__(256)
void split_hi_lo(const float* __restrict__ src, ushort* __restrict__ hi,
                 ushort* __restrict__ lo, int n4) {
    int e = blockIdx.x * 256 + threadIdx.x;
    if (e >= n4) return;
    float4 v = *(const float4*)&src[(size_t)e * 4];
    ushort h0 = f2bf(v.x), h1 = f2bf(v.y), h2 = f2bf(v.z), h3 = f2bf(v.w);
    ushort l0 = f2bf(v.x - bf2f(h0)), l1 = f2bf(v.y - bf2f(h1));
    ushort l2 = f2bf(v.z - bf2f(h2)), l3 = f2bf(v.w - bf2f(h3));
    ushort4 H; H.x = h0; H.y = h1; H.z = h2; H.w = h3;
    ushort4 L; L.x = l0; L.y = l1; L.z = l2; L.w = l3;
    *(ushort4*)&hi[(size_t)e * 4] = H;
    *(ushort4*)&lo[(size_t)e * 4] = L;
}

// ---------------- encoder: split-bf16 MFMA GEMM -> split-bf16 flat ----------
__global__ __launch_bounds__(256)
void enc_mfma(const float* __restrict__ h, const ushort* __restrict__ EWh,
              const ushort* __restrict__ EWl, const float* __restrict__ bias,
              ushort* __restrict__ Fh, ushort* __restrict__ Fl)
{
    constexpr int K = D_DIM, N = KC_DIM;
    __shared__ ushort Ah[128 * 32], Al[128 * 32], Bh[128 * 32], Bl[128 * 32];
    const int gid = blockIdx.x;                 // 1024 blocks
    const int f   = (gid & 7) * 128 + (gid >> 3);
    const int bx  = f & 3, by = f >> 2;         // 4 col-blocks, 256 row-blocks
    const int row0 = by * 128, col0 = bx * 128;
    const int tid  = threadIdx.x;
    const int lane = tid & 63, wave = tid >> 6;
    const int wm = wave >> 1, wn = wave & 1;

    f32x4 acc[4][4];
#pragma unroll
    for (int i = 0; i < 4; ++i)
#pragma unroll
        for (int j = 0; j < 4; ++j)
#pragma unroll
            for (int q = 0; q < 4; ++q) acc[i][j][q] = 0.f;

    const int fr = lane & 15, s4 = lane >> 4;
    const int arow = tid >> 3, ak8 = tid & 7;

    for (int kt = 0; kt < K / 32; ++kt) {
        const int k0 = kt * 32;
#pragma unroll
        for (int r = 0; r < 2; ++r) {
            const int t2 = r * 256 + wave * 64 + lane;
            const int ro = t2 >> 2, sb = t2 & 3;
            const int base = (r * 256 + wave * 64) * 8;
            const size_t gb = (size_t)(col0 + ro) * K + k0 + sb * 8;
            __builtin_amdgcn_global_load_lds(AS1(EWh + gb), AS3(&Bh[base]), 16, 0, 0);
            __builtin_amdgcn_global_load_lds(AS1(EWl + gb), AS3(&Bl[base]), 16, 0, 0);
        }
#pragma unroll
        for (int q = 0; q < 4; ++q) {
            const int row = q * 32 + arow;
            float4 v = *(const float4*)&h[(size_t)(row0 + row) * K + k0 + ak8 * 4];
            ushort h0 = f2bf(v.x), h1 = f2bf(v.y), h2 = f2bf(v.z), h3 = f2bf(v.w);
            ushort l0 = f2bf(v.x - bf2f(h0)), l1 = f2bf(v.y - bf2f(h1));
            ushort l2 = f2bf(v.z - bf2f(h2)), l3 = f2bf(v.w - bf2f(h3));
            ushort4 H; H.x = h0; H.y = h1; H.z = h2; H.w = h3;
            ushort4 L; L.x = l0; L.y = l1; L.z = l2; L.w = l3;
            *(ushort4*)&Ah[row * 32 + ak8 * 4] = H;
            *(ushort4*)&Al[row * 32 + ak8 * 4] = L;
        }
        __syncthreads();

        bf16x8 ah[4], al[4], bh[4], bl[4];
#pragma unroll
        for (int mi = 0; mi < 4; ++mi) {
            const int off = (wm * 64 + mi * 16 + fr) * 32 + s4 * 8;
            ah[mi] = *(const bf16x8*)&Ah[off];
            al[mi] = *(const bf16x8*)&Al[off];
        }
#pragma unroll
        for (int ni = 0; ni < 4; ++ni) {
            const int off = (wn * 64 + ni * 16 + fr) * 32 + s4 * 8;
            bh[ni] = *(const bf16x8*)&Bh[off];
            bl[ni] = *(const bf16x8*)&Bl[off];
        }
#pragma unroll
        for (int mi = 0; mi < 4; ++mi)
#pragma unroll
            for (int ni = 0; ni < 4; ++ni) {
                acc[mi][ni] = __builtin_amdgcn_mfma_f32_16x16x32_bf16(ah[mi], bh[ni], acc[mi][ni], 0, 0, 0);
                acc[mi][ni] = __builtin_amdgcn_mfma_f32_16x16x32_bf16(ah[mi], bl[ni], acc[mi][ni], 0, 0, 0);
                acc[mi][ni] = __builtin_amdgcn_mfma_f32_16x16x32_bf16(al[mi], bh[ni], acc[mi][ni], 0, 0, 0);
            }
        __syncthreads();
    }

    // epilogue: flat value -> split bf16 planes
#pragma unroll
    for (int ni = 0; ni < 4; ++ni) {
        const int c = col0 + wn * 64 + ni * 16 + fr;
        const float bv = bias[c];
#pragma unroll
        for (int mi = 0; mi < 4; ++mi) {
            const int r = row0 + wm * 64 + mi * 16 + s4 * 4;
#pragma unroll
            for (int q = 0; q < 4; ++q) {
                float val = acc[mi][ni][q] + bv;
                ushort hi = f2bf(val);
                ushort lo = f2bf(val - bf2f(hi));
                size_t e = (size_t)(r + q) * N + c;
                Fh[e] = hi;
                Fl[e] = lo;
            }
        }
    }
}

// ---------------- dist on matrix cores: all-bf16 inputs, DMA-staged ----------
__global__ __launch_bounds__(256)
void dist_mfma(const ushort* __restrict__ Fh, const ushort* __restrict__ Fl,
               const ushort* __restrict__ cbh, const ushort* __restrict__ cbl,
               const float* __restrict__ xsq, const float* __restrict__ esq,
               float* __restrict__ pmin, float* __restrict__ psec,
               int* __restrict__ pidx)
{
    constexpr int K = C_DIM;                    // 128
    __shared__ ushort Ah[128 * 32], Al[128 * 32], Bh[128 * 32], Bl[128 * 32];
    const int gid = blockIdx.x;                 // 4096 blocks
    const int f   = (gid & 7) * 512 + (gid >> 3);
    const int bx  = f & 3, by = f >> 2;         // 4 col-blocks, 1024 row-blocks
    const int row0 = by * 128, col0 = bx * 128;
    const int tid  = threadIdx.x;
    const int lane = tid & 63, wave = tid >> 6;
    const int wm = wave >> 1, wn = wave & 1;

    f32x4 acc[4][4];
#pragma unroll
    for (int i = 0; i < 4; ++i)
#pragma unroll
        for (int j = 0; j < 4; ++j)
#pragma unroll
            for (int q = 0; q < 4; ++q) acc[i][j][q] = 0.f;

    const int fr = lane & 15, s4 = lane >> 4;

    for (int kt = 0; kt < K / 32; ++kt) {
        const int k0 = kt * 32;
#pragma unroll
        for (int r = 0; r < 2; ++r) {
            const int t2 = r * 256 + wave * 64 + lane;
            const int ro = t2 >> 2, sb = t2 & 3;
            const int base = (r * 256 + wave * 64) * 8;
            const size_t ga = (size_t)(row0 + ro) * K + k0 + sb * 8;
            const size_t gb = (size_t)(col0 + ro) * K + k0 + sb * 8;
            __builtin_amdgcn_global_load_lds(AS1(Fh + ga), AS3(&Ah[base]), 16, 0, 0);
            __builtin_amdgcn_global_load_lds(AS1(Fl + ga), AS3(&Al[base]), 16, 0, 0);
            __builtin_amdgcn_global_load_lds(AS1(cbh + gb), AS3(&Bh[base]), 16, 0, 0);
            __builtin_amdgcn_global_load_lds(AS1(cbl + gb), AS3(&Bl[base]), 16, 0, 0);
        }
        __syncthreads();

        bf16x8 ah[4], al[4], bh[4], bl[4];
#pragma unroll
        for (int mi = 0; mi < 4; ++mi) {
            const int off = (wm * 64 + mi * 16 + fr) * 32 + s4 * 8;
            ah[mi] = *(const bf16x8*)&Ah[off];
            al[mi] = *(const bf16x8*)&Al[off];
        }
#pragma unroll
        for (int ni = 0; ni < 4; ++ni) {
            const int off = (wn * 64 + ni * 16 + fr) * 32 + s4 * 8;
            bh[ni] = *(const bf16x8*)&Bh[off];
            bl[ni] = *(const bf16x8*)&Bl[off];
        }
#pragma unroll
        for (int mi = 0; mi < 4; ++mi)
#pragma unroll
            for (int ni = 0; ni < 4; ++ni) {
                acc[mi][ni] = __builtin_amdgcn_mfma_f32_16x16x32_bf16(ah[mi], bh[ni], acc[mi][ni], 0, 0, 0);
                acc[mi][ni] = __builtin_amdgcn_mfma_f32_16x16x32_bf16(ah[mi], bl[ni], acc[mi][ni], 0, 0, 0);
                acc[mi][ni] = __builtin_amdgcn_mfma_f32_16x16x32_bf16(al[mi], bh[ni], acc[mi][ni], 0, 0, 0);
            }
        __syncthreads();
    }

    // epilogue: dist + per-row (best, second, idx). LDS scratch aliases Ah/Al
    float* bB = (float*)Ah;          // [128][2]
    float* sB = (float*)Ah + 256;    // [128][2]
    int*   iB = (int*)Al;            // [128][2]

    float es_v[4];
#pragma unroll
    for (int ni = 0; ni < 4; ++ni) es_v[ni] = esq[col0 + wn * 64 + ni * 16 + fr];

#pragma unroll
    for (int mi = 0; mi < 4; ++mi) {
#pragma unroll
        for (int q = 0; q < 4; ++q) {
            const int r = wm * 64 + mi * 16 + s4 * 4 + q;
            const float xs = xsq[row0 + r];
            float b = FLT_BIG, s = FLT_BIG; int bi = 0;
#pragma unroll
            for (int ni = 0; ni < 4; ++ni) {
                float d = (xs - 2.0f * acc[mi][ni][q]) + es_v[ni];
                int c = col0 + wn * 64 + ni * 16 + fr;
                if (d < b) { s = b; b = d; bi = c; }
                else       { s = fminf(s, d); }
            }
#pragma unroll
            for (int m = 1; m < 16; m <<= 1) {
                float b2 = __shfl_xor(b, m);
                float s2 = __shfl_xor(s, m);
                int   i2 = __shfl_xor(bi, m);
                if (b2 < b || (b2 == b && i2 < bi)) { s = fminf(b, s2); b = b2; bi = i2; }
                else                                { s = fminf(s, b2); }
            }
            if (fr == 0) { bB[r * 2 + wn] = b; sB[r * 2 + wn] = s; iB[r * 2 + wn] = bi; }
        }
    }
    __syncthreads();
    if (tid < 128) {
        float b0 = bB[tid * 2],     s0 = sB[tid * 2];     int i0 = iB[tid * 2];
        float b1 = bB[tid * 2 + 1], s1 = sB[tid * 2 + 1]; int i1 = iB[tid * 2 + 1];
        float b, s; int ix;
        if (b1 < b0) { b = b1; s = fminf(b0, s1); ix = i1; }
        else         { b = b0; s = fminf(s0, b1); ix = i0; }
        size_t o = (size_t)(row0 + tid) * 4 + bx;
        pmin[o] = b; psec[o] = s; pidx[o] = ix;
    }
}

// ---------------- merge 4 col-blocks -> idx + near-tie flags ----------------
__global__ __launch_bounds__(256)
void merge_flag(const float* __restrict__ pmin, const float* __restrict__ psec,
                const int* __restrict__ pidx, int* __restrict__ idx_int,
                float* __restrict__ idx_f, int* __restrict__ rowlist,
                int* __restrict__ nflag) {
    int row = blockIdx.x * 256 + threadIdx.x;
    size_t base = (size_t)row * 4;
    float b = pmin[base], sde = psec[base]; int ix = pidx[base];
#pragma unroll
    for (int nb = 1; nb < 4; ++nb) {
        float b2 = pmin[base + nb], s2 = psec[base + nb];
        if (b2 < b) { sde = fminf(b, s2); b = b2; ix = pidx[base + nb]; }
        else        { sde = fminf(sde, b2); }
    }
    idx_int[row] = ix;
    idx_f[row] = (float)ix;
    if (sde - b < GAP_EPS) {
        int p = atomicAdd(nflag, 1);
        rowlist[p] = row;
    }
}

// ---------------- exact recompute of near-tie rows (numpy-bit-exact) ----------
__global__ __launch_bounds__(256)
void refine_rows(const float* __restrict__ h, const float* __restrict__ enc_w,
                 const float* __restrict__ enc_b, const float* __restrict__ cb,
                 const float* __restrict__ esq, const int* __restrict__ rowlist,
                 const int* __restrict__ nflag_p, int* __restrict__ idx_int,
                 float* __restrict__ idx_f)
{
    __shared__ __align__(16) float x[C_DIM];
    __shared__ float xs_sh;
    __shared__ float rb[256];
    __shared__ int   ri[256];
    const int tid = threadIdx.x;
    const int nf = *nflag_p;
    for (int fi = blockIdx.x; fi < nf; fi += gridDim.x) {
        const int row = rowlist[fi];
        const int bt = row >> 2, seg = row & 3;
        if (tid < C_DIM) {
            const float* hp = h + (size_t)bt * D_DIM;
            const float* wp = enc_w + (size_t)(seg * C_DIM + tid) * D_DIM;
            float acc = 0.f, accC = 0.f;
            int fold = 96;   // 384/4
#pragma unroll 8
            for (int d = 0; d < D_DIM; d += 4) {
                float4 hv = *(const float4*)(hp + d);
                float4 wv = *(const float4*)(wp + d);
                accC = fmaf(hv.x, wv.x, accC);
                accC = fmaf(hv.y, wv.y, accC);
                accC = fmaf(hv.z, wv.z, accC);
                accC = fmaf(hv.w, wv.w, accC);
                if (--fold == 0) { acc = __fadd_rn(acc, accC); accC = 0.f; fold = 96; }
            }
            acc = __fadd_rn(acc, accC);   // K%384=128 remainder
            x[tid] = __fadd_rn(acc, enc_b[seg * C_DIM + tid]);
        }
        __syncthreads();
        if (tid == 0) {
            float rj[8];
#pragma unroll
            for (int j = 0; j < 8; ++j) rj[j] = __fmul_rn(x[j], x[j]);
            for (int i = 1; i < 16; ++i)
#pragma unroll
                for (int j = 0; j < 8; ++j)
                    rj[j] = __fadd_rn(rj[j], __fmul_rn(x[i * 8 + j], x[i * 8 + j]));
            float a01 = __fadd_rn(rj[0], rj[1]);
            float a23 = __fadd_rn(rj[2], rj[3]);
            float a45 = __fadd_rn(rj[4], rj[5]);
            float a67 = __fadd_rn(rj[6], rj[7]);
            xs_sh = __fadd_rn(__fadd_rn(a01, a23), __fadd_rn(a45, a67));
        }
        __syncthreads();
        const float xs = xs_sh;
        float best; int bi;
        {
            const int c0 = tid * 2;
            const float* e0 = cb + (size_t)c0 * C_DIM;
            float dot0 = 0.f, dot1 = 0.f;
#pragma unroll 4
            for (int c = 0; c < C_DIM; c += 4) {
                float4 xv  = *(const float4*)&x[c];
                float4 ev0 = *(const float4*)(e0 + c);
                float4 ev1 = *(const float4*)(e0 + C_DIM + c);
                dot0 = fmaf(xv.x, ev0.x, dot0); dot0 = fmaf(xv.y, ev0.y, dot0);
                dot0 = fmaf(xv.z, ev0.z, dot0); dot0 = fmaf(xv.w, ev0.w, dot0);
                dot1 = fmaf(xv.x, ev1.x, dot1); dot1 = fmaf(xv.y, ev1.y, dot1);
                dot1 = fmaf(xv.z, ev1.z, dot1); dot1 = fmaf(xv.w, ev1.w, dot1);
            }
            float d0 = __fadd_rn(__fsub_rn(xs, __fmul_rn(2.0f, dot0)), esq[c0]);
            float d1 = __fadd_rn(__fsub_rn(xs, __fmul_rn(2.0f, dot1)), esq[c0 + 1]);
            if (d1 < d0) { best = d1; bi = c0 + 1; } else { best = d0; bi = c0; }
        }
        rb[tid] = best; ri[tid] = bi;
        __syncthreads();
        for (int st = 128; st; st >>= 1) {
            if (tid < st) {
                float d2 = rb[tid + st]; int i2 = ri[tid + st];
                if (d2 < rb[tid] || (d2 == rb[tid] && i2 < ri[tid])) {
                    rb[tid] = d2; ri[tid] = i2;
                }
            }
            __syncthreads();
        }
        if (tid == 0) { idx_int[row] = ri[0]; idx_f[row] = (float)ri[0]; }
        __syncthreads();
    }
}

// ---------------- histogram over final indices ----------------
__global__ __launch_bounds__(256)
void histogram_kernel(const int* __restrict__ idx_int, unsigned* __restrict__ counts) {
    __shared__ unsigned hist[NCODES];
    int t = threadIdx.x;
    hist[t] = 0u; hist[t + 256] = 0u;
    __syncthreads();
    int row = blockIdx.x * 256 + t;
    atomicAdd(&hist[idx_int[row]], 1u);
    __syncthreads();
    if (hist[t]) atomicAdd(&counts[t], hist[t]);
    if (hist[t + 256]) atomicAdd(&counts[t + 256], hist[t + 256]);
}

// ---------------- loss from split-bf16 flat ----------------
__global__ __launch_bounds__(256)
void gather_loss_bf(const ushort* __restrict__ Fh, const ushort* __restrict__ Fl,
                    const int* __restrict__ idx, const float* __restrict__ cb,
                    float* __restrict__ loss_sum) {
    size_t e0 = ((size_t)blockIdx.x * 256 + threadIdx.x) * 8;
    int n = (int)(e0 >> 7);
    int c = (int)(e0 & 127);
    int k = idx[n];
    const float4* qp = (const float4*)(cb + (size_t)k * C_DIM + c);
    float4 q0 = qp[0], q1 = qp[1];
    ushort4 h0 = *(const ushort4*)&Fh[e0], h1 = *(const ushort4*)&Fh[e0 + 4];
    ushort4 l0 = *(const ushort4*)&Fl[e0], l1 = *(const ushort4*)&Fl[e0 + 4];
    float s = 0.f, d;
    d = q0.x - (bf2f(h0.x) + bf2f(l0.x)); s += d * d;
    d = q0.y - (bf2f(h0.y) + bf2f(l0.y)); s += d * d;
    d = q0.z - (bf2f(h0.z) + bf2f(l0.z)); s += d * d;
    d = q0.w - (bf2f(h0.w) + bf2f(l0.w)); s += d * d;
    d = q1.x - (bf2f(h1.x) + bf2f(l1.x)); s += d * d;
    d = q1.y - (bf2f(h1.y) + bf2f(l1.y)); s += d * d;
    d = q1.z - (bf2f(h1.z) + bf2f(l1.z)); s += d * d;
    d = q1.w - (bf2f(h1.w) + bf2f(l1.w)); s += d * d;

    __shared__ float redf[256];
    redf[threadIdx.x] = s;
    __syncthreads();
    for (int st = 128; st; st >>= 1) {
        if (threadIdx.x < st) redf[threadIdx.x] += redf[threadIdx.x + st];
        __syncthreads();
    }
    if (threadIdx.x == 0) atomicAdd(loss_sum, redf[0]);
}

// ---------------- gather split-bf16 quantized rows ----------------
__global__ __launch_bounds__(256)
void build_q(const int* __restrict__ idx, const ushort* __restrict__ cbh,
             const ushort* __restrict__ cbl, ushort* __restrict__ Qh,
             ushort* __restrict__ Ql) {
    int t = blockIdx.x * 256 + threadIdx.x;   // 16B chunk id
    int n = t >> 4, c8 = t & 15;
    int k = idx[n];
    uint4 vh = *(const uint4*)&cbh[(size_t)k * C_DIM + c8 * 8];
    uint4 vl = *(const uint4*)&cbl[(size_t)k * C_DIM + c8 * 8];
    *(uint4*)&Qh[(size_t)n * C_DIM + c8 * 8] = vh;
    *(uint4*)&Ql[(size_t)n * C_DIM + c8 * 8] = vl;
}

// ---------------- decoder: split-bf16 MFMA GEMM, XCD-swizzled 1-D grid ----------------
__global__ __launch_bounds__(256)
void dec_gemm_bf16(const ushort* __restrict__ Qh, const ushort* __restrict__ Ql,
                   const ushort* __restrict__ Wh, const ushort* __restrict__ Wl,
                   const float* __restrict__ bias, float* __restrict__ C)
{
    constexpr int Kd = 512, Nd = 2048;
    __shared__ ushort Ah[128 * 32], Al[128 * 32], Bh[128 * 32], Bl[128 * 32];
    const int gid = blockIdx.x;                       // 4096 blocks
    const int f   = (gid & 7) * 512 + (gid >> 3);
    const int bx  = f & 15, by = f >> 4;
    const int tid  = threadIdx.x;
    const int lane = tid & 63, wave = tid >> 6;
    const int wm = wave >> 1, wn = wave & 1;
    const int row0 = by * 128, col0 = bx * 128;

    f32x4 acc[4][4];
#pragma unroll
    for (int i = 0; i < 4; ++i)
#pragma unroll
        for (int j = 0; j < 4; ++j)
#pragma unroll
            for (int q = 0; q < 4; ++q) acc[i][j][q] = 0.f;

    const int fr = lane & 15, s4 = lane >> 4;

    for (int kt = 0; kt < Kd / 32; ++kt) {
        const int k0 = kt * 32;
#pragma unroll
        for (int r = 0; r < 2; ++r) {
            const int t2 = r * 256 + wave * 64 + lane;
            const int ro = t2 >> 2, sb = t2 & 3;
            const int base = (r * 256 + wave * 64) * 8;
            const size_t ga = (size_t)(row0 + ro) * Kd + k0 + sb * 8;
            const size_t gb = (size_t)(col0 + ro) * Kd + k0 + sb * 8;
            __builtin_amdgcn_global_load_lds(AS1(Qh + ga), AS3(&Ah[base]), 16, 0, 0);
            __builtin_amdgcn_global_load_lds(AS1(Ql + ga), AS3(&Al[base]), 16, 0, 0);
            __builtin_amdgcn_global_load_lds(AS1(Wh + gb), AS3(&Bh[base]), 16, 0, 0);
            __builtin_amdgcn_global_load_lds(AS1(Wl + gb), AS3(&Bl[base]), 16, 0, 0);
        }
        __syncthreads();

        bf16x8 ah[4], al[4], bh[4], bl[4];
#pragma unroll
        for (int mi = 0; mi < 4; ++mi) {
            const int off = (wm * 64 + mi * 16 + fr) * 32 + s4 * 8;
            ah[mi] = *(const bf16x8*)&Ah[off];
            al[mi] = *(const bf16x8*)&Al[off];
        }
#pragma unroll
        for (int ni = 0; ni < 4; ++ni) {
            const int off = (wn * 64 + ni * 16 + fr) * 32 + s4 * 8;
            bh[ni] = *(const bf16x8*)&Bh[off];
            bl[ni] = *(const bf16x8*)&Bl[off];
        }
#pragma unroll
        for (int mi = 0; mi < 4; ++mi)
#pragma unroll
            for (int ni = 0; ni < 4; ++ni) {
                acc[mi][ni] = __builtin_amdgcn_mfma_f32_16x16x32_bf16(ah[mi], bh[ni], acc[mi][ni], 0, 0, 0);
                acc[mi][ni] = __builtin_amdgcn_mfma_f32_16x16x32_bf16(ah[mi], bl[ni], acc[mi][ni], 0, 0, 0);
                acc[mi][ni] = __builtin_amdgcn_mfma_f32_16x16x32_bf16(al[mi], bh[ni], acc[mi][ni], 0, 0, 0);
            }
        __syncthreads();
    }

#pragma unroll
    for (int ni = 0; ni < 4; ++ni) {
        const int c = col0 + wn * 64 + ni * 16 + fr;
        const float bv = bias[c];
#pragma unroll
        for (int mi = 0; mi < 4; ++mi) {
            const int r = row0 + wm * 64 + mi * 16 + s4 * 4;
#pragma unroll
            for (int q = 0; q < 4; ++q)
                C[(size_t)(r + q) * Nd + c] = acc[mi][ni][q] + bv;
        }
    }
}

// ---------------- scalars ----------------
__global__ __launch_bounds__(512)
void finalize_scalars(const unsigned* __restrict__ counts,
                      const float* __restrict__ loss_sum, float* __restrict__ out5) {
    __shared__ float rent[512];
    __shared__ float ruse[512];
    int t = threadIdx.x;
    float c = (float)counts[t];
    float avg = c * (1.0f / (float)NROWS);
    rent[t] = avg * logf(avg + 1e-10f);
    ruse[t] = counts[t] > 0u ? 1.f : 0.f;
    __syncthreads();
    for (int st = 256; st; st >>= 1) {
        if (t < st) { rent[t] += rent[t + st]; ruse[t] += ruse[t + st]; }
        __syncthreads();
    }
    if (t == 0) {
        float H = -rent[0];
        float perp = expf(H);
        float cl = loss_sum[0] * (1.0f / (float)NELEM);
        out5[0] = cl + 0.25f * cl;
        out5[1] = cl;
        out5[2] = cl;
        out5[3] = perp;
        out5[4] = ruse[0] * (1.0f / (float)NCODES);
    }
}

extern "C" void kernel_launch(void* const* d_in, const int* in_sizes, int n_in,
                              void* d_out, int out_size, void* d_ws, size_t ws_size,
                              hipStream_t stream) {
    const float* h     = (const float*)d_in[0];
    const float* enc_w = (const float*)d_in[1];
    const float* enc_b = (const float*)d_in[2];
    const float* cb    = (const float*)d_in[3];
    const float* dec_w = (const float*)d_in[4];
    const float* dec_b = (const float*)d_in[5];
    float* out = (float*)d_out;

    float* ws = (float*)d_ws;
    // flat now lives as two bf16 planes in [0, 16777216) float-slots
    ushort*   Fh       = (ushort*)ws;                // 16M ushorts = [0, 8388608)f
    ushort*   Fl       = (ushort*)(ws + 8388608);    // 16M ushorts = [8388608, 16777216)f
    float*    xsq      = ws + 16777216;              // 131072
    float*    pmin     = ws + 16908288;              // 524288
    float*    psec     = ws + 17432576;              // 524288
    int*      pidx     = (int*)(ws + 17956864);      // 524288
    int*      idx_int  = (int*)(ws + 18481152);      // 131072
    int*      rowlist  = (int*)(ws + 18612224);      // 131072
    float*    esq      = ws + 18743296;              // 512
    unsigned* counts   = (unsigned*)(ws + 18743808); // 512
    float*    loss_sum = ws + 18744320;              // 1
    int*      nflag    = (int*)(ws + 18744321);      // 1

    // overlays (hosts dead when used). cb split planes each = 32768 float-slots.
    ushort* EWh  = (ushort*)(ws + 16908288);         // over pmin  (pre-dist)
    ushort* EWl  = (ushort*)(ws + 17432576);         // over psec  (pre-dist)
    ushort* cbhd = (ushort*)(ws + 18612224);         // over rowlist[0..32767]   (pre-merge)
    ushort* cbld = (ushort*)(ws + 18644992);         // over rowlist[32768..65535]
    ushort* cbh  = (ushort*)(ws + 16777216);         // over xsq[0..32767]       (post-dist)
    ushort* cbl  = (ushort*)(ws + 16809984);         // over xsq[32768..65535]
    ushort* Wh   = (ushort*)(ws + 16908288);         // over pmin (post-merge)
    ushort* Wl   = (ushort*)(ws + 17432576);         // over psec (post-merge)
    ushort* Qh   = (ushort*)ws;                      // over Fh (post-loss)
    ushort* Ql   = (ushort*)(ws + 8388608);          // over Fl (post-loss)

    float* msg_out = out;                     // 67108864
    float* idx_out = out + 67108864;          // 131072
    float* sc_out  = out + 67108864 + 131072; // 5

    zero_kernel<<<1, 512, 0, stream>>>(counts, loss_sum, nflag);
    sq_pairwise<<<NCODES / 32, 256, 0, stream>>>(cb, esq, NCODES);

    // split enc_w -> bf16 hi/lo (overlay pmin/psec; dead until dist)
    split_hi_lo<<<KC_DIM * D_DIM / 4 / 256, 256, 0, stream>>>(enc_w, EWh, EWl, KC_DIM * D_DIM / 4);
    // split cb -> bf16 hi/lo for dist (overlay rowlist; dead until merge)
    split_hi_lo<<<NCODES * C_DIM / 4 / 256, 256, 0, stream>>>(cb, cbhd, cbld, NCODES * C_DIM / 4);

    // encoder on matrix cores -> split-bf16 flat planes
    enc_mfma<<<1024, 256, 0, stream>>>(h, EWh, EWl, enc_b, Fh, Fl);

    sq_pairwise_bf<<<NROWS / 32, 256, 0, stream>>>(Fh, Fl, xsq, NROWS);

    // distances on matrix cores (all-bf16, DMA-staged) + best/second/idx
    dist_mfma<<<4096, 256, 0, stream>>>(Fh, Fl, cbhd, cbld, xsq, esq, pmin, psec, pidx);

    merge_flag<<<NROWS / 256, 256, 0, stream>>>(pmin, psec, pidx, idx_int, idx_out,
                                                rowlist, nflag);

    // exact numpy-faithful recompute for near-tie rows
    refine_rows<<<2048, 256, 0, stream>>>(h, enc_w, enc_b, cb, esq, rowlist, nflag,
                                          idx_int, idx_out);

    histogram_kernel<<<NROWS / 256, 256, 0, stream>>>(idx_int, counts);

    gather_loss_bf<<<NELEM / (256 * 8), 256, 0, stream>>>(Fh, Fl, idx_int, cb, loss_sum);

    // splits for decoder (xsq / pmin / psec dead now)
    split_hi_lo<<<NCODES * C_DIM / 4 / 256, 256, 0, stream>>>(cb, cbh, cbl, NCODES * C_DIM / 4);
    split_hi_lo<<<D_DIM * KC_DIM / 4 / 256, 256, 0, stream>>>(dec_w, Wh, Wl, D_DIM * KC_DIM / 4);

    // Fh/Fl dead -> gather quantized bf16 rows into their space
    build_q<<<NROWS * 16 / 256, 256, 0, stream>>>(idx_int, cbh, cbl, Qh, Ql);

    dec_gemm_bf16<<<4096, 256, 0, stream>>>(Qh, Ql, Wh, Wl, dec_b, msg_out);

    finalize_scalars<<<1, 512, 0, stream>>>(counts, loss_sum, sc_out);
}